// Round 6
// baseline (38384.995 us; speedup 1.0000x reference)
//
#include <hip/hip_runtime.h>

#define D_MODEL 1024
#define NGROUPS 8
#define SUB 8192
#define TOPK 32
#define BATCH 2048
#define NTOT (NGROUPS * SUB)   // 65536

// ---------------- Phase A: fp32 GEMM, BLAS-sgemm-exact (kc=384 K-blocking) ----------------
// per element: P_i = sequential FMA chain over k in [384i, min(384(i+1),1024));
// C = ((P0 + P1) + P2) with rounded fp32 adds; pre = C + b_enc (one rounded add).
// 128x128 tile, BK=16, 8x8 micro-tile, double-buffered LDS, early-issue staging.
#define BM 128
#define BN 128
#define BK 16
#define LDSA 132   // padded stride for As[k][m] (transposed scatter writes)
#define LDSB 128   // Bs[k][n] unpadded: linear rows for global_load_lds

typedef float v4f __attribute__((ext_vector_type(4)));

__global__ __launch_bounds__(256, 3) void sae_encode_gemm(
    const float* __restrict__ x,
    const float* __restrict__ W_enc,
    const float* __restrict__ b_enc,
    float* __restrict__ out_acts)
{
    __shared__ float As[2][BK * LDSA];
    __shared__ float Bs[2][BK * LDSB];

    const int tid = threadIdx.x;
    const int nt = blockIdx.x;          // 0..511 (N tiles, fast-varying)
    const int mt = blockIdx.y;          // 0..15  (M tiles)
    const int g = nt >> 6;
    const int sbase = (nt & 63) * BN;
    const int mbase = mt * BM;

    const float* Bp = W_enc + ((size_t)g * D_MODEL) * SUB + sbase;
    const float* Ap = x + (size_t)mbase * D_MODEL;

    // A staging: row ar (0..127), col offset ac (0 or 8): 2 float4 per thread
    const int ar = tid >> 1;
    const int ac = (tid & 1) * 8;
    const float* Arow = Ap + (size_t)ar * D_MODEL + ac;

    // B staging via global_load_lds: wave wv handles k-rows 4wv..4wv+3 (2 DMA x 2 rows)
    const int wv = tid >> 6;
    const int ln = tid & 63;
    const int brow_off = ln >> 5;          // 0/1
    const int bcol = (ln & 31) * 4;

    // micro-tile position
    const int tr = tid >> 4;               // 0..15 -> rows tr*8..+8
    const int tc = tid & 15;               // 0..15 -> cols tc*4 and tc*4+64

    float tot[8][8], cur[8][8];
#pragma unroll
    for (int i = 0; i < 8; ++i)
#pragma unroll
        for (int j = 0; j < 8; ++j) { tot[i][j] = 0.0f; cur[i][j] = 0.0f; }

    // ---- prologue: stage tile 0 into buffer 0 ----
    {
        const v4f a0 = *reinterpret_cast<const v4f*>(Arow);
        const v4f a1 = *reinterpret_cast<const v4f*>(Arow + 4);
#pragma unroll
        for (int t = 0; t < 2; ++t) {
            const int r0 = 4 * wv + 2 * t;
            const float* gsrc = Bp + (size_t)(r0 + brow_off) * SUB + bcol;
            __builtin_amdgcn_global_load_lds(
                (const __attribute__((address_space(1))) void*)gsrc,
                (__attribute__((address_space(3))) void*)&Bs[0][r0 * LDSB],
                16, 0, 0);
        }
#pragma unroll
        for (int j = 0; j < 4; ++j) {
            As[0][(ac + j) * LDSA + ar]     = a0[j];
            As[0][(ac + 4 + j) * LDSA + ar] = a1[j];
        }
        __syncthreads();
    }

    // ---- main loop: 64 K-steps, one barrier each, folds at k=384 (it=24) and 768 (it=48) ----
#pragma unroll 1
    for (int it = 0; it < 64; ++it) {
        const int cb = it & 1;
        const int nb = cb ^ 1;
        const bool has_next = (it < 63);
        const int k0n = (it + 1) * BK;

        v4f a0, a1;
        if (has_next) {
            // early-issue next tile: A global->regs, B global->LDS DMA
            a0 = *reinterpret_cast<const v4f*>(Arow + k0n);
            a1 = *reinterpret_cast<const v4f*>(Arow + k0n + 4);
#pragma unroll
            for (int t = 0; t < 2; ++t) {
                const int r0 = 4 * wv + 2 * t;
                const float* gsrc = Bp + (size_t)(k0n + r0 + brow_off) * SUB + bcol;
                __builtin_amdgcn_global_load_lds(
                    (const __attribute__((address_space(1))) void*)gsrc,
                    (__attribute__((address_space(3))) void*)&Bs[nb][r0 * LDSB],
                    16, 0, 0);
            }
        }

        // fold at BLAS K-block boundaries (before computing k=384 / k=768)
        if (it == 24 || it == 48) {
#pragma unroll
            for (int i = 0; i < 8; ++i)
#pragma unroll
                for (int j = 0; j < 8; ++j) {
                    tot[i][j] = __fadd_rn(tot[i][j], cur[i][j]);
                    cur[i][j] = 0.0f;
                }
        }

        // compute current tile from LDS
#pragma unroll
        for (int kk = 0; kk < BK; ++kk) {
            float a[8], bb[8];
            *reinterpret_cast<v4f*>(&a[0])  = *reinterpret_cast<const v4f*>(&As[cb][kk * LDSA + tr * 8]);
            *reinterpret_cast<v4f*>(&a[4])  = *reinterpret_cast<const v4f*>(&As[cb][kk * LDSA + tr * 8 + 4]);
            *reinterpret_cast<v4f*>(&bb[0]) = *reinterpret_cast<const v4f*>(&Bs[cb][kk * LDSB + tc * 4]);
            *reinterpret_cast<v4f*>(&bb[4]) = *reinterpret_cast<const v4f*>(&Bs[cb][kk * LDSB + tc * 4 + 64]);
#pragma unroll
            for (int i = 0; i < 8; ++i)
#pragma unroll
                for (int j = 0; j < 8; ++j)
                    cur[i][j] = fmaf(a[i], bb[j], cur[i][j]);
        }

        // late write of A stage (vmcnt wait on a0/a1 inserted by compiler)
        if (has_next) {
#pragma unroll
            for (int j = 0; j < 4; ++j) {
                As[nb][(ac + j) * LDSA + ar]     = a0[j];
                As[nb][(ac + 4 + j) * LDSA + ar] = a1[j];
            }
        }
        __syncthreads();
    }

    // final fold: tot = (P0 + P1) + P2
#pragma unroll
    for (int i = 0; i < 8; ++i)
#pragma unroll
        for (int j = 0; j < 8; ++j)
            tot[i][j] = __fadd_rn(tot[i][j], cur[i][j]);

    // epilogue: single rounded fp32 bias add, store pre
    const float* bias = b_enc + (size_t)g * SUB + sbase;
    const float4 bb0 = *reinterpret_cast<const float4*>(bias + tc * 4);
    const float4 bb1 = *reinterpret_cast<const float4*>(bias + tc * 4 + 64);
    float* outp = out_acts + (size_t)g * SUB + sbase;
#pragma unroll
    for (int i = 0; i < 8; ++i) {
        const size_t row = (size_t)(mbase + tr * 8 + i);
        const float4 o0 = make_float4(__fadd_rn(tot[i][0], bb0.x), __fadd_rn(tot[i][1], bb0.y),
                                      __fadd_rn(tot[i][2], bb0.z), __fadd_rn(tot[i][3], bb0.w));
        const float4 o1 = make_float4(__fadd_rn(tot[i][4], bb1.x), __fadd_rn(tot[i][5], bb1.y),
                                      __fadd_rn(tot[i][6], bb1.z), __fadd_rn(tot[i][7], bb1.w));
        *reinterpret_cast<float4*>(outp + row * NTOT + tc * 4) = o0;
        *reinterpret_cast<float4*>(outp + row * NTOT + tc * 4 + 64) = o1;
    }
}

// ---------------- Phase B: per-row exact top-32 (fp32 keys, lowest-index ties), rewrite, decode ----------------
#define PIDX(s) ((s) + ((s) >> 5))

__device__ __forceinline__ unsigned fkey(float f) {
    unsigned u = __float_as_uint(f);
    return (u & 0x80000000u) ? ~u : (u | 0x80000000u);
}

__global__ __launch_bounds__(256) void sae_topk_decode(
    const float* __restrict__ W_dec,
    float* __restrict__ out_recon,
    float* __restrict__ out_acts)
{
    __shared__ float row[SUB + (SUB >> 5)];
    __shared__ unsigned hist[256];
    __shared__ unsigned sscan[256];
    __shared__ unsigned wsum[4];
    __shared__ unsigned wsum2[4];
    __shared__ unsigned sh_bin, sh_above;
    __shared__ int   sel_idx[TOPK];
    __shared__ float sel_val[TOPK];

    const int tid = threadIdx.x;
    const int lane = tid & 63;
    const int w = tid >> 6;
    const size_t b = blockIdx.x;

    float r0 = 0.f, r1 = 0.f, r2 = 0.f, r3 = 0.f;

    for (int g = 0; g < NGROUPS; ++g) {
        float* rowg = out_acts + b * NTOT + (size_t)g * SUB;

#pragma unroll
        for (int t = 0; t < 8; ++t) {
            const int i4 = tid + t * 256;
            const float4 v = *reinterpret_cast<const float4*>(rowg + (size_t)i4 * 4);
            const int s0 = i4 * 4;
            row[PIDX(s0) + 0] = v.x;
            row[PIDX(s0) + 1] = v.y;
            row[PIDX(s0) + 2] = v.z;
            row[PIDX(s0) + 3] = v.w;
        }
        __syncthreads();

        unsigned prefix = 0;
        unsigned kwant = TOPK;
#pragma unroll
        for (int r = 0; r < 4; ++r) {
            const int shift = 24 - 8 * r;
            hist[tid] = 0;
            __syncthreads();
            for (int j = 0; j < 32; ++j) {
                const unsigned key = fkey(row[tid * 33 + j]);
                const unsigned hi = (unsigned)(((unsigned long long)key) >> (shift + 8));
                const unsigned pi = (unsigned)(((unsigned long long)prefix) >> (shift + 8));
                if (hi == pi) atomicAdd(&hist[(key >> shift) & 255u], 1u);
            }
            __syncthreads();
            const unsigned hv = hist[tid];
            unsigned s = hv;
#pragma unroll
            for (int off = 1; off < 64; off <<= 1) {
                const unsigned o = __shfl_down(s, off, 64);
                if (lane + off < 64) s += o;
            }
            if (lane == 0) wsum[w] = s;
            __syncthreads();
            unsigned add = 0;
            for (int w2 = w + 1; w2 < 4; ++w2) add += wsum[w2];
            s += add;
            sscan[tid] = s;
            __syncthreads();
            const unsigned snext = (tid < 255) ? sscan[tid + 1] : 0u;
            if (s >= kwant && snext < kwant) { sh_bin = (unsigned)tid; sh_above = snext; }
            __syncthreads();
            prefix |= sh_bin << shift;
            kwant -= sh_above;
            __syncthreads();
        }
        const unsigned T = prefix;
        const unsigned n_take = kwant;
        const unsigned cnt_gt_total = TOPK - n_take;

        unsigned loc_gt = 0, loc_eq = 0;
        for (int j = 0; j < 32; ++j) {
            const unsigned key = fkey(row[tid * 33 + j]);
            loc_gt += (key > T);
            loc_eq += (key == T);
        }
        const unsigned pack = loc_gt | (loc_eq << 16);
        unsigned sI = pack;
#pragma unroll
        for (int off = 1; off < 64; off <<= 1) {
            const unsigned o = __shfl_up(sI, off, 64);
            if (lane >= off) sI += o;
        }
        if (lane == 63) wsum2[w] = sI;
        __syncthreads();
        unsigned woff = 0;
        for (int w2 = 0; w2 < w; ++w2) woff += wsum2[w2];
        const unsigned excl = sI - pack + woff;
        unsigned run_gt = excl & 0xFFFFu;
        unsigned run_eq = excl >> 16;

        for (int j = 0; j < 32; ++j) {
            const int sidx = tid * 32 + j;
            const float f = row[tid * 33 + j];
            const unsigned key = fkey(f);
            const float act = fmaxf(f, 0.0f);
            if (key > T) {
                sel_idx[run_gt] = sidx; sel_val[run_gt] = act; ++run_gt;
                row[tid * 33 + j] = act;
            } else if (key == T) {
                if (run_eq < n_take) {
                    sel_idx[cnt_gt_total + run_eq] = sidx;
                    sel_val[cnt_gt_total + run_eq] = act;
                    row[tid * 33 + j] = act;
                } else {
                    row[tid * 33 + j] = 0.0f;
                }
                ++run_eq;
            } else {
                row[tid * 33 + j] = 0.0f;
            }
        }
        __syncthreads();

#pragma unroll
        for (int t = 0; t < 8; ++t) {
            const int i4 = tid + t * 256;
            const int s0 = i4 * 4;
            const float4 v = make_float4(row[PIDX(s0) + 0], row[PIDX(s0) + 1],
                                         row[PIDX(s0) + 2], row[PIDX(s0) + 3]);
            *reinterpret_cast<float4*>(rowg + (size_t)i4 * 4) = v;
        }

        const float* Wg = W_dec + (size_t)g * SUB * D_MODEL + tid * 4;
#pragma unroll 8
        for (int j = 0; j < TOPK; ++j) {
            const float v = sel_val[j];
            const float4 wv = *reinterpret_cast<const float4*>(Wg + (size_t)sel_idx[j] * D_MODEL);
            r0 = fmaf(v, wv.x, r0); r1 = fmaf(v, wv.y, r1);
            r2 = fmaf(v, wv.z, r2); r3 = fmaf(v, wv.w, r3);
        }
        __syncthreads();
    }

    *reinterpret_cast<float4*>(out_recon + b * D_MODEL + tid * 4) = make_float4(r0, r1, r2, r3);
}

extern "C" void kernel_launch(void* const* d_in, const int* in_sizes, int n_in,
                              void* d_out, int out_size, void* d_ws, size_t ws_size,
                              hipStream_t stream) {
    const float* x     = (const float*)d_in[0];
    const float* W_enc = (const float*)d_in[1];
    const float* b_enc = (const float*)d_in[2];
    const float* W_dec = (const float*)d_in[3];

    float* out_recon = (float*)d_out;
    float* out_acts  = (float*)d_out + (size_t)BATCH * D_MODEL;

    dim3 gridA(NTOT / BN, BATCH / BM);   // (512, 16)
    sae_encode_gemm<<<gridA, 256, 0, stream>>>(x, W_enc, b_enc, out_acts);
    sae_topk_decode<<<BATCH, 256, 0, stream>>>(W_dec, out_recon, out_acts);
}

// Round 7
// 5116.969 us; speedup vs baseline: 7.5015x; 7.5015x over previous
//
#include <hip/hip_runtime.h>

#define D_MODEL 1024
#define NGROUPS 8
#define SUB 8192
#define TOPK 32
#define BATCH 2048
#define NTOT (NGROUPS * SUB)   // 65536

// ---------------- Phase A: fp32 GEMM, BLAS-sgemm-exact (kc=384 K-blocking) ----------------
// per element: P_i = sequential FMA chain over k in [384i, min(384(i+1),1024));
// C = ((P0 + P1) + P2) with rounded fp32 adds; pre = C + b_enc (one rounded add).
// R5 chassis (single-buffer LDS, 2 barriers/K-step, plain loads) + 8x8 micro-tile.
// NOTE: no min-waves launch_bounds cap — R6 showed (256,3) + dbuf spills the
// 128-float accumulator set to scratch (WRITE_SIZE 0.5->106 GB, 10x slowdown).
#define BM 128
#define BN 128
#define BK 16
#define LDSA 132   // padded stride for As[k][m]
#define LDSB 128   // Bs[k][n] linear

typedef float v4f __attribute__((ext_vector_type(4)));

__global__ __launch_bounds__(256) void sae_encode_gemm(
    const float* __restrict__ x,
    const float* __restrict__ W_enc,
    const float* __restrict__ b_enc,
    float* __restrict__ out_acts)
{
    __shared__ float As[BK * LDSA];  // As[k][m] transposed
    __shared__ float Bs[BK * LDSB];  // Bs[k][n]

    const int tid = threadIdx.x;
    const int nt = blockIdx.x;          // 0..511 (N tiles)
    const int mt = blockIdx.y;          // 0..15  (M tiles)
    const int g = nt >> 6;
    const int sbase = (nt & 63) * BN;
    const int mbase = mt * BM;

    const float* Bp = W_enc + ((size_t)g * D_MODEL) * SUB + sbase;
    const float* Ap = x + (size_t)mbase * D_MODEL;

    // A staging: each thread loads 8 cols of one row (2 float4), scatters transposed
    const int a_m = tid >> 1;            // 0..127
    const int a_c = (tid & 1) * 8;       // 0 or 8
    // B staging: each thread 2 rows (b_k, b_k+8), 1 float4 each
    const int b_k = tid >> 5;            // 0..7
    const int b_c = (tid & 31) * 4;      // 0..124

    const int tr = tid >> 4;             // 0..15 -> rows tr*8..+8
    const int tc = tid & 15;             // 0..15 -> cols tc*4 and tc*4+64

    float tot[8][8], cur[8][8];
#pragma unroll
    for (int i = 0; i < 8; ++i)
#pragma unroll
        for (int j = 0; j < 8; ++j) { tot[i][j] = 0.0f; cur[i][j] = 0.0f; }

#pragma unroll 1
    for (int it = 0; it < 64; ++it) {
        const int k0 = it * BK;

        // global loads (prev-iter trailing barrier protects LDS reuse)
        const v4f va0 = *reinterpret_cast<const v4f*>(Ap + (size_t)a_m * D_MODEL + k0 + a_c);
        const v4f va1 = *reinterpret_cast<const v4f*>(Ap + (size_t)a_m * D_MODEL + k0 + a_c + 4);
        const v4f vb0 = *reinterpret_cast<const v4f*>(Bp + (size_t)(k0 + b_k) * SUB + b_c);
        const v4f vb1 = *reinterpret_cast<const v4f*>(Bp + (size_t)(k0 + b_k + 8) * SUB + b_c);

        // LDS stores
#pragma unroll
        for (int j = 0; j < 4; ++j) {
            As[(a_c + j) * LDSA + a_m]     = va0[j];
            As[(a_c + 4 + j) * LDSA + a_m] = va1[j];
        }
        *reinterpret_cast<v4f*>(&Bs[b_k * LDSB + b_c])       = vb0;
        *reinterpret_cast<v4f*>(&Bs[(b_k + 8) * LDSB + b_c]) = vb1;
        __syncthreads();

        // fold at BLAS K-block boundaries (k = 384, 768)
        if (it == 24 || it == 48) {
#pragma unroll
            for (int i = 0; i < 8; ++i)
#pragma unroll
                for (int j = 0; j < 8; ++j) {
                    tot[i][j] = __fadd_rn(tot[i][j], cur[i][j]);
                    cur[i][j] = 0.0f;
                }
        }

        // compute: 1024 FMA per thread per K-step, 4 ds_read_b128 per kk
#pragma unroll
        for (int kk = 0; kk < BK; ++kk) {
            float a[8], bb[8];
            *reinterpret_cast<v4f*>(&a[0])  = *reinterpret_cast<const v4f*>(&As[kk * LDSA + tr * 8]);
            *reinterpret_cast<v4f*>(&a[4])  = *reinterpret_cast<const v4f*>(&As[kk * LDSA + tr * 8 + 4]);
            *reinterpret_cast<v4f*>(&bb[0]) = *reinterpret_cast<const v4f*>(&Bs[kk * LDSB + tc * 4]);
            *reinterpret_cast<v4f*>(&bb[4]) = *reinterpret_cast<const v4f*>(&Bs[kk * LDSB + tc * 4 + 64]);
#pragma unroll
            for (int i = 0; i < 8; ++i)
#pragma unroll
                for (int j = 0; j < 8; ++j)
                    cur[i][j] = fmaf(a[i], bb[j], cur[i][j]);
        }
        __syncthreads();
    }

    // final fold: tot = (P0 + P1) + P2
#pragma unroll
    for (int i = 0; i < 8; ++i)
#pragma unroll
        for (int j = 0; j < 8; ++j)
            tot[i][j] = __fadd_rn(tot[i][j], cur[i][j]);

    // epilogue: single rounded fp32 bias add, store pre
    const float* bias = b_enc + (size_t)g * SUB + sbase;
    const float4 bb0 = *reinterpret_cast<const float4*>(bias + tc * 4);
    const float4 bb1 = *reinterpret_cast<const float4*>(bias + tc * 4 + 64);
    float* outp = out_acts + (size_t)g * SUB + sbase;
#pragma unroll
    for (int i = 0; i < 8; ++i) {
        const size_t row = (size_t)(mbase + tr * 8 + i);
        const float4 o0 = make_float4(__fadd_rn(tot[i][0], bb0.x), __fadd_rn(tot[i][1], bb0.y),
                                      __fadd_rn(tot[i][2], bb0.z), __fadd_rn(tot[i][3], bb0.w));
        const float4 o1 = make_float4(__fadd_rn(tot[i][4], bb1.x), __fadd_rn(tot[i][5], bb1.y),
                                      __fadd_rn(tot[i][6], bb1.z), __fadd_rn(tot[i][7], bb1.w));
        *reinterpret_cast<float4*>(outp + row * NTOT + tc * 4) = o0;
        *reinterpret_cast<float4*>(outp + row * NTOT + tc * 4 + 64) = o1;
    }
}

// ---------------- Phase B: per-row exact top-32 (fp32 keys, lowest-index ties), rewrite, decode ----------------
#define PIDX(s) ((s) + ((s) >> 5))

__device__ __forceinline__ unsigned fkey(float f) {
    unsigned u = __float_as_uint(f);
    return (u & 0x80000000u) ? ~u : (u | 0x80000000u);
}

__global__ __launch_bounds__(256) void sae_topk_decode(
    const float* __restrict__ W_dec,
    float* __restrict__ out_recon,
    float* __restrict__ out_acts)
{
    __shared__ float row[SUB + (SUB >> 5)];
    __shared__ unsigned hist[256];
    __shared__ unsigned sscan[256];
    __shared__ unsigned wsum[4];
    __shared__ unsigned wsum2[4];
    __shared__ unsigned sh_bin, sh_above;
    __shared__ int   sel_idx[TOPK];
    __shared__ float sel_val[TOPK];

    const int tid = threadIdx.x;
    const int lane = tid & 63;
    const int w = tid >> 6;
    const size_t b = blockIdx.x;

    float r0 = 0.f, r1 = 0.f, r2 = 0.f, r3 = 0.f;

    for (int g = 0; g < NGROUPS; ++g) {
        float* rowg = out_acts + b * NTOT + (size_t)g * SUB;

#pragma unroll
        for (int t = 0; t < 8; ++t) {
            const int i4 = tid + t * 256;
            const float4 v = *reinterpret_cast<const float4*>(rowg + (size_t)i4 * 4);
            const int s0 = i4 * 4;
            row[PIDX(s0) + 0] = v.x;
            row[PIDX(s0) + 1] = v.y;
            row[PIDX(s0) + 2] = v.z;
            row[PIDX(s0) + 3] = v.w;
        }
        __syncthreads();

        unsigned prefix = 0;
        unsigned kwant = TOPK;
#pragma unroll
        for (int r = 0; r < 4; ++r) {
            const int shift = 24 - 8 * r;
            hist[tid] = 0;
            __syncthreads();
            for (int j = 0; j < 32; ++j) {
                const unsigned key = fkey(row[tid * 33 + j]);
                const unsigned hi = (unsigned)(((unsigned long long)key) >> (shift + 8));
                const unsigned pi = (unsigned)(((unsigned long long)prefix) >> (shift + 8));
                if (hi == pi) atomicAdd(&hist[(key >> shift) & 255u], 1u);
            }
            __syncthreads();
            const unsigned hv = hist[tid];
            unsigned s = hv;
#pragma unroll
            for (int off = 1; off < 64; off <<= 1) {
                const unsigned o = __shfl_down(s, off, 64);
                if (lane + off < 64) s += o;
            }
            if (lane == 0) wsum[w] = s;
            __syncthreads();
            unsigned add = 0;
            for (int w2 = w + 1; w2 < 4; ++w2) add += wsum[w2];
            s += add;
            sscan[tid] = s;
            __syncthreads();
            const unsigned snext = (tid < 255) ? sscan[tid + 1] : 0u;
            if (s >= kwant && snext < kwant) { sh_bin = (unsigned)tid; sh_above = snext; }
            __syncthreads();
            prefix |= sh_bin << shift;
            kwant -= sh_above;
            __syncthreads();
        }
        const unsigned T = prefix;
        const unsigned n_take = kwant;
        const unsigned cnt_gt_total = TOPK - n_take;

        unsigned loc_gt = 0, loc_eq = 0;
        for (int j = 0; j < 32; ++j) {
            const unsigned key = fkey(row[tid * 33 + j]);
            loc_gt += (key > T);
            loc_eq += (key == T);
        }
        const unsigned pack = loc_gt | (loc_eq << 16);
        unsigned sI = pack;
#pragma unroll
        for (int off = 1; off < 64; off <<= 1) {
            const unsigned o = __shfl_up(sI, off, 64);
            if (lane >= off) sI += o;
        }
        if (lane == 63) wsum2[w] = sI;
        __syncthreads();
        unsigned woff = 0;
        for (int w2 = 0; w2 < w; ++w2) woff += wsum2[w2];
        const unsigned excl = sI - pack + woff;
        unsigned run_gt = excl & 0xFFFFu;
        unsigned run_eq = excl >> 16;

        for (int j = 0; j < 32; ++j) {
            const int sidx = tid * 32 + j;
            const float f = row[tid * 33 + j];
            const unsigned key = fkey(f);
            const float act = fmaxf(f, 0.0f);
            if (key > T) {
                sel_idx[run_gt] = sidx; sel_val[run_gt] = act; ++run_gt;
                row[tid * 33 + j] = act;
            } else if (key == T) {
                if (run_eq < n_take) {
                    sel_idx[cnt_gt_total + run_eq] = sidx;
                    sel_val[cnt_gt_total + run_eq] = act;
                    row[tid * 33 + j] = act;
                } else {
                    row[tid * 33 + j] = 0.0f;
                }
                ++run_eq;
            } else {
                row[tid * 33 + j] = 0.0f;
            }
        }
        __syncthreads();

#pragma unroll
        for (int t = 0; t < 8; ++t) {
            const int i4 = tid + t * 256;
            const int s0 = i4 * 4;
            const float4 v = make_float4(row[PIDX(s0) + 0], row[PIDX(s0) + 1],
                                         row[PIDX(s0) + 2], row[PIDX(s0) + 3]);
            *reinterpret_cast<float4*>(rowg + (size_t)i4 * 4) = v;
        }

        const float* Wg = W_dec + (size_t)g * SUB * D_MODEL + tid * 4;
#pragma unroll 8
        for (int j = 0; j < TOPK; ++j) {
            const float v = sel_val[j];
            const float4 wv = *reinterpret_cast<const float4*>(Wg + (size_t)sel_idx[j] * D_MODEL);
            r0 = fmaf(v, wv.x, r0); r1 = fmaf(v, wv.y, r1);
            r2 = fmaf(v, wv.z, r2); r3 = fmaf(v, wv.w, r3);
        }
        __syncthreads();
    }

    *reinterpret_cast<float4*>(out_recon + b * D_MODEL + tid * 4) = make_float4(r0, r1, r2, r3);
}

extern "C" void kernel_launch(void* const* d_in, const int* in_sizes, int n_in,
                              void* d_out, int out_size, void* d_ws, size_t ws_size,
                              hipStream_t stream) {
    const float* x     = (const float*)d_in[0];
    const float* W_enc = (const float*)d_in[1];
    const float* b_enc = (const float*)d_in[2];
    const float* W_dec = (const float*)d_in[3];

    float* out_recon = (float*)d_out;
    float* out_acts  = (float*)d_out + (size_t)BATCH * D_MODEL;

    dim3 gridA(NTOT / BN, BATCH / BM);   // (512, 16)
    sae_encode_gemm<<<gridA, 256, 0, stream>>>(x, W_enc, b_enc, out_acts);
    sae_topk_decode<<<BATCH, 256, 0, stream>>>(W_dec, out_recon, out_acts);
}

// Round 8
// 4619.467 us; speedup vs baseline: 8.3094x; 1.1077x over previous
//
#include <hip/hip_runtime.h>

#define D_MODEL 1024
#define NGROUPS 8
#define SUB 8192
#define TOPK 32
#define BATCH 2048
#define NTOT (NGROUPS * SUB)   // 65536

// ---------------- Phase A: fp32 GEMM, BLAS-sgemm-exact (kc=384 K-blocking) ----------------
// per element: P_i = sequential FMA chain over k in [384i, min(384(i+1),1024));
// C = ((P0 + P1) + P2) with rounded fp32 adds; pre = C + b_enc (one rounded add).
// R5 chassis (4x8 micro-tile, VGPR~64-100 class, single-buffer LDS, 2 barriers/K-step)
// with BK=32: halves barrier+staging overhead per FMA.
// Occupancy lesson (R6/R7): keep per-thread registers low — TLP across barriers
// beats per-thread FMA density on this structure.
#define BM 64
#define BN 128
#define BK 32
#define LDSA 68    // padded stride for As[k][m]
#define LDSB 132   // padded stride for Bs[k][n]

typedef float v4f __attribute__((ext_vector_type(4)));

__global__ __launch_bounds__(256) void sae_encode_gemm(
    const float* __restrict__ x,
    const float* __restrict__ W_enc,
    const float* __restrict__ b_enc,
    float* __restrict__ out_acts)
{
    __shared__ float As[BK * LDSA];  // 32x68 floats = 8.7 KB
    __shared__ float Bs[BK * LDSB];  // 32x132 floats = 16.9 KB

    const int tid = threadIdx.x;
    const int nt = blockIdx.x;          // 0..511 (N tiles)
    const int mt = blockIdx.y;          // 0..31  (M tiles)
    const int g = nt >> 6;
    const int sbase = (nt & 63) * BN;
    const int mbase = mt * BM;

    const float* Bp = W_enc + ((size_t)g * D_MODEL) * SUB + sbase;
    const float* Ap = x + (size_t)mbase * D_MODEL;

    // A staging: 64 rows x 32 cols = 8 floats/thread (2 float4)
    const int a_m = tid >> 2;            // 0..63
    const int a_c = (tid & 3) * 8;       // 0,8,16,24
    // B staging: 32 rows x 128 cols = 16 floats/thread (4 float4)
    const int b_k = tid >> 5;            // 0..7 -> rows b_k + 8h
    const int b_c = (tid & 31) * 4;      // 0..124

    const int tr = tid >> 4;             // 0..15 -> rows tr*4..+4
    const int tc = tid & 15;             // 0..15 -> cols tc*4 and tc*4+64

    float tot[4][8], cur[4][8];
#pragma unroll
    for (int i = 0; i < 4; ++i)
#pragma unroll
        for (int j = 0; j < 8; ++j) { tot[i][j] = 0.0f; cur[i][j] = 0.0f; }

#pragma unroll 1
    for (int it = 0; it < D_MODEL / BK; ++it) {   // 32 iterations
        const int k0 = it * BK;

        // global loads
        const v4f va0 = *reinterpret_cast<const v4f*>(Ap + (size_t)a_m * D_MODEL + k0 + a_c);
        const v4f va1 = *reinterpret_cast<const v4f*>(Ap + (size_t)a_m * D_MODEL + k0 + a_c + 4);
        v4f vb[4];
#pragma unroll
        for (int h = 0; h < 4; ++h)
            vb[h] = *reinterpret_cast<const v4f*>(Bp + (size_t)(k0 + b_k + 8 * h) * SUB + b_c);

        // LDS stores
#pragma unroll
        for (int j = 0; j < 4; ++j) {
            As[(a_c + j) * LDSA + a_m]     = va0[j];
            As[(a_c + 4 + j) * LDSA + a_m] = va1[j];
        }
#pragma unroll
        for (int h = 0; h < 4; ++h)
            *reinterpret_cast<v4f*>(&Bs[(b_k + 8 * h) * LDSB + b_c]) = vb[h];
        __syncthreads();

        // fold at BLAS K-block boundaries (k = 384 -> it 12, k = 768 -> it 24)
        if (it == 12 || it == 24) {
#pragma unroll
            for (int i = 0; i < 4; ++i)
#pragma unroll
                for (int j = 0; j < 8; ++j) {
                    tot[i][j] = __fadd_rn(tot[i][j], cur[i][j]);
                    cur[i][j] = 0.0f;
                }
        }

        // compute: 1024 FMA per thread per K-step, 3 ds_read_b128 per kk
#pragma unroll
        for (int kk = 0; kk < BK; ++kk) {
            float a[4], bb[8];
            *reinterpret_cast<v4f*>(&a[0])  = *reinterpret_cast<const v4f*>(&As[kk * LDSA + tr * 4]);
            *reinterpret_cast<v4f*>(&bb[0]) = *reinterpret_cast<const v4f*>(&Bs[kk * LDSB + tc * 4]);
            *reinterpret_cast<v4f*>(&bb[4]) = *reinterpret_cast<const v4f*>(&Bs[kk * LDSB + tc * 4 + 64]);
#pragma unroll
            for (int i = 0; i < 4; ++i)
#pragma unroll
                for (int j = 0; j < 8; ++j)
                    cur[i][j] = fmaf(a[i], bb[j], cur[i][j]);
        }
        __syncthreads();
    }

    // final fold: tot = (P0 + P1) + P2
#pragma unroll
    for (int i = 0; i < 4; ++i)
#pragma unroll
        for (int j = 0; j < 8; ++j)
            tot[i][j] = __fadd_rn(tot[i][j], cur[i][j]);

    // epilogue: single rounded fp32 bias add, store pre
    const float* bias = b_enc + (size_t)g * SUB + sbase;
    const float4 bb0 = *reinterpret_cast<const float4*>(bias + tc * 4);
    const float4 bb1 = *reinterpret_cast<const float4*>(bias + tc * 4 + 64);
    float* outp = out_acts + (size_t)g * SUB + sbase;
#pragma unroll
    for (int i = 0; i < 4; ++i) {
        const size_t row = (size_t)(mbase + tr * 4 + i);
        const float4 o0 = make_float4(__fadd_rn(tot[i][0], bb0.x), __fadd_rn(tot[i][1], bb0.y),
                                      __fadd_rn(tot[i][2], bb0.z), __fadd_rn(tot[i][3], bb0.w));
        const float4 o1 = make_float4(__fadd_rn(tot[i][4], bb1.x), __fadd_rn(tot[i][5], bb1.y),
                                      __fadd_rn(tot[i][6], bb1.z), __fadd_rn(tot[i][7], bb1.w));
        *reinterpret_cast<float4*>(outp + row * NTOT + tc * 4) = o0;
        *reinterpret_cast<float4*>(outp + row * NTOT + tc * 4 + 64) = o1;
    }
}

// ---------------- Phase B: per-row exact top-32 (fp32 keys, lowest-index ties), rewrite, decode ----------------
#define PIDX(s) ((s) + ((s) >> 5))

__device__ __forceinline__ unsigned fkey(float f) {
    unsigned u = __float_as_uint(f);
    return (u & 0x80000000u) ? ~u : (u | 0x80000000u);
}

__global__ __launch_bounds__(256) void sae_topk_decode(
    const float* __restrict__ W_dec,
    float* __restrict__ out_recon,
    float* __restrict__ out_acts)
{
    __shared__ float row[SUB + (SUB >> 5)];
    __shared__ unsigned hist[256];
    __shared__ unsigned sscan[256];
    __shared__ unsigned wsum[4];
    __shared__ unsigned wsum2[4];
    __shared__ unsigned sh_bin, sh_above;
    __shared__ int   sel_idx[TOPK];
    __shared__ float sel_val[TOPK];

    const int tid = threadIdx.x;
    const int lane = tid & 63;
    const int w = tid >> 6;
    const size_t b = blockIdx.x;

    float r0 = 0.f, r1 = 0.f, r2 = 0.f, r3 = 0.f;

    for (int g = 0; g < NGROUPS; ++g) {
        float* rowg = out_acts + b * NTOT + (size_t)g * SUB;

#pragma unroll
        for (int t = 0; t < 8; ++t) {
            const int i4 = tid + t * 256;
            const float4 v = *reinterpret_cast<const float4*>(rowg + (size_t)i4 * 4);
            const int s0 = i4 * 4;
            row[PIDX(s0) + 0] = v.x;
            row[PIDX(s0) + 1] = v.y;
            row[PIDX(s0) + 2] = v.z;
            row[PIDX(s0) + 3] = v.w;
        }
        __syncthreads();

        unsigned prefix = 0;
        unsigned kwant = TOPK;
#pragma unroll
        for (int r = 0; r < 4; ++r) {
            const int shift = 24 - 8 * r;
            hist[tid] = 0;
            __syncthreads();
            for (int j = 0; j < 32; ++j) {
                const unsigned key = fkey(row[tid * 33 + j]);
                const unsigned hi = (unsigned)(((unsigned long long)key) >> (shift + 8));
                const unsigned pi = (unsigned)(((unsigned long long)prefix) >> (shift + 8));
                if (hi == pi) atomicAdd(&hist[(key >> shift) & 255u], 1u);
            }
            __syncthreads();
            const unsigned hv = hist[tid];
            unsigned s = hv;
#pragma unroll
            for (int off = 1; off < 64; off <<= 1) {
                const unsigned o = __shfl_down(s, off, 64);
                if (lane + off < 64) s += o;
            }
            if (lane == 0) wsum[w] = s;
            __syncthreads();
            unsigned add = 0;
            for (int w2 = w + 1; w2 < 4; ++w2) add += wsum[w2];
            s += add;
            sscan[tid] = s;
            __syncthreads();
            const unsigned snext = (tid < 255) ? sscan[tid + 1] : 0u;
            if (s >= kwant && snext < kwant) { sh_bin = (unsigned)tid; sh_above = snext; }
            __syncthreads();
            prefix |= sh_bin << shift;
            kwant -= sh_above;
            __syncthreads();
        }
        const unsigned T = prefix;
        const unsigned n_take = kwant;
        const unsigned cnt_gt_total = TOPK - n_take;

        unsigned loc_gt = 0, loc_eq = 0;
        for (int j = 0; j < 32; ++j) {
            const unsigned key = fkey(row[tid * 33 + j]);
            loc_gt += (key > T);
            loc_eq += (key == T);
        }
        const unsigned pack = loc_gt | (loc_eq << 16);
        unsigned sI = pack;
#pragma unroll
        for (int off = 1; off < 64; off <<= 1) {
            const unsigned o = __shfl_up(sI, off, 64);
            if (lane >= off) sI += o;
        }
        if (lane == 63) wsum2[w] = sI;
        __syncthreads();
        unsigned woff = 0;
        for (int w2 = 0; w2 < w; ++w2) woff += wsum2[w2];
        const unsigned excl = sI - pack + woff;
        unsigned run_gt = excl & 0xFFFFu;
        unsigned run_eq = excl >> 16;

        for (int j = 0; j < 32; ++j) {
            const int sidx = tid * 32 + j;
            const float f = row[tid * 33 + j];
            const unsigned key = fkey(f);
            const float act = fmaxf(f, 0.0f);
            if (key > T) {
                sel_idx[run_gt] = sidx; sel_val[run_gt] = act; ++run_gt;
                row[tid * 33 + j] = act;
            } else if (key == T) {
                if (run_eq < n_take) {
                    sel_idx[cnt_gt_total + run_eq] = sidx;
                    sel_val[cnt_gt_total + run_eq] = act;
                    row[tid * 33 + j] = act;
                } else {
                    row[tid * 33 + j] = 0.0f;
                }
                ++run_eq;
            } else {
                row[tid * 33 + j] = 0.0f;
            }
        }
        __syncthreads();

#pragma unroll
        for (int t = 0; t < 8; ++t) {
            const int i4 = tid + t * 256;
            const int s0 = i4 * 4;
            const float4 v = make_float4(row[PIDX(s0) + 0], row[PIDX(s0) + 1],
                                         row[PIDX(s0) + 2], row[PIDX(s0) + 3]);
            *reinterpret_cast<float4*>(rowg + (size_t)i4 * 4) = v;
        }

        const float* Wg = W_dec + (size_t)g * SUB * D_MODEL + tid * 4;
#pragma unroll 8
        for (int j = 0; j < TOPK; ++j) {
            const float v = sel_val[j];
            const float4 wv = *reinterpret_cast<const float4*>(Wg + (size_t)sel_idx[j] * D_MODEL);
            r0 = fmaf(v, wv.x, r0); r1 = fmaf(v, wv.y, r1);
            r2 = fmaf(v, wv.z, r2); r3 = fmaf(v, wv.w, r3);
        }
        __syncthreads();
    }

    *reinterpret_cast<float4*>(out_recon + b * D_MODEL + tid * 4) = make_float4(r0, r1, r2, r3);
}

extern "C" void kernel_launch(void* const* d_in, const int* in_sizes, int n_in,
                              void* d_out, int out_size, void* d_ws, size_t ws_size,
                              hipStream_t stream) {
    const float* x     = (const float*)d_in[0];
    const float* W_enc = (const float*)d_in[1];
    const float* b_enc = (const float*)d_in[2];
    const float* W_dec = (const float*)d_in[3];

    float* out_recon = (float*)d_out;
    float* out_acts  = (float*)d_out + (size_t)BATCH * D_MODEL;

    dim3 gridA(NTOT / BN, BATCH / BM);   // (512, 32)
    sae_encode_gemm<<<gridA, 256, 0, stream>>>(x, W_enc, b_enc, out_acts);
    sae_topk_decode<<<BATCH, 256, 0, stream>>>(W_dec, out_recon, out_acts);
}

// Round 10
// 3725.201 us; speedup vs baseline: 10.3041x; 1.2401x over previous
//
#include <hip/hip_runtime.h>

#define D_MODEL 1024
#define NGROUPS 8
#define SUB 8192
#define TOPK 32
#define BATCH 2048
#define NTOT (NGROUPS * SUB)   // 65536

typedef float v4f __attribute__((ext_vector_type(4)));
typedef _Float16 f16x8 __attribute__((ext_vector_type(8)));
typedef float f32x4 __attribute__((ext_vector_type(4)));

__device__ __forceinline__ unsigned fkey(float f) {
    unsigned u = __float_as_uint(f);
    return (u & 0x80000000u) ? ~u : (u | 0x80000000u);  // monotonic
}
__device__ __forceinline__ float inv_fkey(unsigned key) {
    unsigned u = (key & 0x80000000u) ? (key & 0x7FFFFFFFu) : ~key;
    return __uint_as_float(u);
}
__device__ __forceinline__ unsigned pack2h(float a, float b) {
    _Float16 ha = (_Float16)a, hb = (_Float16)b;
    return (unsigned)__builtin_bit_cast(unsigned short, ha)
         | ((unsigned)__builtin_bit_cast(unsigned short, hb) << 16);
}

// ================= k1: transpose W_enc [g][k][s] -> WT [g][s][k] =================
__global__ __launch_bounds__(256) void transpose_wenc(
    const float* __restrict__ W, float* __restrict__ WT)
{
    __shared__ float t[32][33];
    const int g = blockIdx.z, kt = blockIdx.y, st = blockIdx.x;
    const int lx = threadIdx.x & 31, ly = threadIdx.x >> 5;   // ly 0..7
    const float* Wg = W + (size_t)g * D_MODEL * SUB;
    float* WTg = WT + (size_t)g * SUB * D_MODEL;
#pragma unroll
    for (int r = 0; r < 4; ++r)
        t[ly + 8 * r][lx] = Wg[(size_t)(kt * 32 + ly + 8 * r) * SUB + st * 32 + lx];
    __syncthreads();
#pragma unroll
    for (int r = 0; r < 4; ++r)
        WTg[(size_t)(st * 32 + ly + 8 * r) * D_MODEL + kt * 32 + lx] = t[lx][ly + 8 * r];
}

// ================= k2: f16 MFMA approx scores = x @ W_enc + b_enc ================
__global__ __launch_bounds__(256) void mfma_scores(
    const float* __restrict__ x, const float* __restrict__ W_enc,
    const float* __restrict__ b_enc, float* __restrict__ scores)
{
    __shared__ _Float16 Ah[128 * 40];   // [m][k] stride 40
    __shared__ unsigned Bp[16 * 132];   // [k-pair][s] stride 132 (f16x2 packed)

    const int tid = threadIdx.x;
    const int mt = blockIdx.x, nt = blockIdx.y;   // mt fast => W-strip reuse in L2
    const int g = nt >> 6;
    const int sbase = (nt & 63) * 128;
    const int mbase = mt * 128;

    const float* Bg = W_enc + (size_t)g * D_MODEL * SUB + sbase;
    const int lane = tid & 63, w = tid >> 6;
    const int wm = w >> 1, wn = w & 1;
    const int l15 = lane & 15, grp = lane >> 4;

    const int am = tid >> 1, akh = (tid & 1) * 16;        // A staging
    const int bk4 = (tid >> 5) * 4, bs4 = (tid & 31) * 4; // B staging

    f32x4 acc[4][4];
#pragma unroll
    for (int i = 0; i < 4; ++i)
#pragma unroll
        for (int j = 0; j < 4; ++j) acc[i][j] = (f32x4){0.f, 0.f, 0.f, 0.f};

#pragma unroll 1
    for (int it = 0; it < 32; ++it) {
        const int k0 = it * 32;
        const float* ap = x + (size_t)(mbase + am) * D_MODEL + k0 + akh;
        const v4f a0 = *(const v4f*)(ap);
        const v4f a1 = *(const v4f*)(ap + 4);
        const v4f a2 = *(const v4f*)(ap + 8);
        const v4f a3 = *(const v4f*)(ap + 12);
        v4f br[4];
#pragma unroll
        for (int r = 0; r < 4; ++r)
            br[r] = *(const v4f*)(Bg + (size_t)(k0 + bk4 + r) * SUB + bs4);

        f16x8 v0, v1;
#pragma unroll
        for (int j = 0; j < 4; ++j) {
            v0[j] = (_Float16)a0[j]; v0[4 + j] = (_Float16)a1[j];
            v1[j] = (_Float16)a2[j]; v1[4 + j] = (_Float16)a3[j];
        }
        *(f16x8*)&Ah[am * 40 + akh]     = v0;
        *(f16x8*)&Ah[am * 40 + akh + 8] = v1;
        const int kp0 = bk4 >> 1;
        uint4 p0, p1;
        p0.x = pack2h(br[0][0], br[1][0]); p0.y = pack2h(br[0][1], br[1][1]);
        p0.z = pack2h(br[0][2], br[1][2]); p0.w = pack2h(br[0][3], br[1][3]);
        p1.x = pack2h(br[2][0], br[3][0]); p1.y = pack2h(br[2][1], br[3][1]);
        p1.z = pack2h(br[2][2], br[3][2]); p1.w = pack2h(br[2][3], br[3][3]);
        *(uint4*)&Bp[kp0 * 132 + bs4]       = p0;
        *(uint4*)&Bp[(kp0 + 1) * 132 + bs4] = p1;
        __syncthreads();

        f16x8 af[4], bf[4];
#pragma unroll
        for (int i = 0; i < 4; ++i)
            af[i] = *(const f16x8*)&Ah[(wm * 64 + i * 16 + l15) * 40 + 8 * grp];
#pragma unroll
        for (int j = 0; j < 4; ++j) {
            const int col = wn * 64 + j * 16 + l15;
            uint4 q;
            q.x = Bp[(4 * grp + 0) * 132 + col];
            q.y = Bp[(4 * grp + 1) * 132 + col];
            q.z = Bp[(4 * grp + 2) * 132 + col];
            q.w = Bp[(4 * grp + 3) * 132 + col];
            bf[j] = __builtin_bit_cast(f16x8, q);
        }
#pragma unroll
        for (int i = 0; i < 4; ++i)
#pragma unroll
            for (int j = 0; j < 4; ++j)
                acc[i][j] = __builtin_amdgcn_mfma_f32_16x16x32_f16(af[i], bf[j], acc[i][j], 0, 0, 0);
        __syncthreads();
    }

    float bb[4];
#pragma unroll
    for (int j = 0; j < 4; ++j)
        bb[j] = b_enc[(size_t)g * SUB + sbase + wn * 64 + j * 16 + l15];
#pragma unroll
    for (int i = 0; i < 4; ++i) {
        const int row = mbase + wm * 64 + i * 16 + grp * 4;
#pragma unroll
        for (int j = 0; j < 4; ++j) {
            const size_t col = (size_t)g * SUB + sbase + wn * 64 + j * 16 + l15;
#pragma unroll
            for (int r = 0; r < 4; ++r)
                scores[(size_t)(row + r) * NTOT + col] = __fadd_rn(acc[i][j][r], bb[j]);
        }
    }
}

// ================= k3: select + exact recompute + decode =================
#define PIDX(s) ((s) + ((s) >> 5))
#define CMAX 128

__global__ __launch_bounds__(256) void select_decode(
    const float* __restrict__ x, const float* __restrict__ WT,
    const float* __restrict__ b_enc, const float* __restrict__ W_dec,
    float* __restrict__ out_recon, float* __restrict__ out_acts)
{
    __shared__ float pool[8448];          // srow (PIDX) | cstage 8x1028
    __shared__ float xrow[1024];
    __shared__ unsigned hist[256], sscan[256], wsum[4];
    __shared__ unsigned sh_bin, sh_above, cand_cnt;
    __shared__ int   cand_idx[CMAX];
    __shared__ float cand_val[CMAX];
    __shared__ float pacc[8][3];
    __shared__ int   sel_idx[TOPK];
    __shared__ float sel_val[TOPK];

    const int tid = threadIdx.x;
    const int lane = tid & 63;
    const int w = tid >> 6;
    const size_t b = blockIdx.x;

    *(float4*)&xrow[tid * 4] = *(const float4*)(x + b * D_MODEL + tid * 4);
    float r0 = 0.f, r1 = 0.f, r2 = 0.f, r3 = 0.f;

    for (int g = 0; g < NGROUPS; ++g) {
        float* rowg = out_acts + b * NTOT + (size_t)g * SUB;

        // ---- load approx scores into padded LDS ----
#pragma unroll
        for (int t = 0; t < 8; ++t) {
            const int i4 = tid + t * 256;
            const float4 v = *(const float4*)(rowg + (size_t)i4 * 4);
            const int s0 = i4 * 4;
            pool[PIDX(s0) + 0] = v.x; pool[PIDX(s0) + 1] = v.y;
            pool[PIDX(s0) + 2] = v.z; pool[PIDX(s0) + 3] = v.w;
        }
        __syncthreads();

        // ---- 4-round radix select: 32nd-largest approx key ----
        unsigned prefix = 0, kwant = TOPK;
#pragma unroll
        for (int r = 0; r < 4; ++r) {
            const int shift = 24 - 8 * r;
            hist[tid] = 0;
            __syncthreads();
            for (int j = 0; j < 32; ++j) {
                const unsigned key = fkey(pool[tid * 33 + j]);
                const unsigned hi = (unsigned)(((unsigned long long)key) >> (shift + 8));
                const unsigned pi = (unsigned)(((unsigned long long)prefix) >> (shift + 8));
                if (hi == pi) atomicAdd(&hist[(key >> shift) & 255u], 1u);
            }
            __syncthreads();
            unsigned s = hist[tid];
#pragma unroll
            for (int off = 1; off < 64; off <<= 1) {
                const unsigned o = __shfl_down(s, off, 64);
                if (lane + off < 64) s += o;
            }
            if (lane == 0) wsum[w] = s;
            __syncthreads();
            unsigned add = 0;
            for (int w2 = w + 1; w2 < 4; ++w2) add += wsum[w2];
            s += add;
            sscan[tid] = s;
            __syncthreads();
            const unsigned snext = (tid < 255) ? sscan[tid + 1] : 0u;
            if (s >= kwant && snext < kwant) { sh_bin = (unsigned)tid; sh_above = snext; }
            __syncthreads();
            prefix |= sh_bin << shift;
            kwant -= sh_above;
            __syncthreads();
        }
        const float v32 = inv_fkey(prefix);
        const unsigned wkey = fkey(v32 - 0.06f);   // margin >= 2*delta (delta<=0.025)

        if (tid == 0) cand_cnt = 0;
        __syncthreads();
        for (int j = 0; j < 32; ++j) {
            const float f = pool[tid * 33 + j];
            if (fkey(f) >= wkey) {
                const unsigned slot = atomicAdd(&cand_cnt, 1u);
                if (slot < CMAX) cand_idx[slot] = tid * 32 + j;
            }
        }
        // zero the output row (exact acts scattered later)
#pragma unroll
        for (int t = 0; t < 8; ++t)
            *(float4*)(rowg + (size_t)(tid + t * 256) * 4) = make_float4(0.f, 0.f, 0.f, 0.f);
        __syncthreads();
        const int cnt = min((int)cand_cnt, CMAX);
        const int nb = (cnt + 7) >> 3;

        // ---- exact recompute: batches of 8 candidate columns ----
        for (int bi = 0; bi < nb; ++bi) {
            const int c = tid >> 5;
            const int ci = bi * 8 + c;
            if (ci < cnt) {
                const float* colp = WT + (size_t)g * SUB * D_MODEL + (size_t)cand_idx[ci] * D_MODEL;
#pragma unroll
                for (int i2 = 0; i2 < 8; ++i2) {
                    const int k = (tid & 31) * 4 + i2 * 128;
                    *(float4*)&pool[c * 1028 + k] = *(const float4*)(colp + k);
                }
            }
            __syncthreads();
            if (tid < 24) {
                const int c2 = tid / 3, ch = tid % 3;
                const int ci2 = bi * 8 + c2;
                if (ci2 < cnt) {
                    const int kb = ch * 384, ke = (ch == 2) ? 1024 : (kb + 384);
                    float a = 0.f;
                    for (int k = kb; k < ke; ++k)
                        a = fmaf(xrow[k], pool[c2 * 1028 + k], a);
                    pacc[c2][ch] = a;
                }
            }
            __syncthreads();
            if (tid < 8) {
                const int ci2 = bi * 8 + tid;
                if (ci2 < cnt)
                    cand_val[ci2] = __fadd_rn(
                        __fadd_rn(__fadd_rn(pacc[tid][0], pacc[tid][1]), pacc[tid][2]),
                        b_enc[(size_t)g * SUB + cand_idx[ci2]]);
            }
            __syncthreads();
        }

        // ---- exact top-32 among candidates (val desc, idx asc) ----
        if (tid < cnt) {
            const unsigned mykey = fkey(cand_val[tid]);
            const int myidx = cand_idx[tid];
            int rank = 0;
            for (int e = 0; e < cnt; ++e) {
                const unsigned ke = fkey(cand_val[e]);
                if (ke > mykey || (ke == mykey && cand_idx[e] < myidx)) ++rank;
            }
            if (rank < TOPK) { sel_idx[rank] = myidx; sel_val[rank] = fmaxf(cand_val[tid], 0.f); }
        }
        __syncthreads();
        if (tid < TOPK) rowg[sel_idx[tid]] = sel_val[tid];

        // ---- recon += sum_j act_j * W_dec[g][s_j][:] ----
        const float* Wg = W_dec + (size_t)g * SUB * D_MODEL + tid * 4;
#pragma unroll 8
        for (int j = 0; j < TOPK; ++j) {
            const float v = sel_val[j];
            const float4 wv = *(const float4*)(Wg + (size_t)sel_idx[j] * D_MODEL);
            r0 = fmaf(v, wv.x, r0); r1 = fmaf(v, wv.y, r1);
            r2 = fmaf(v, wv.z, r2); r3 = fmaf(v, wv.w, r3);
        }
        __syncthreads();
    }
    *(float4*)(out_recon + b * D_MODEL + tid * 4) = make_float4(r0, r1, r2, r3);
}

// ================= Fallback: R5 exact fp32 path (if ws too small) =================
#define BM 64
#define BN 128
#define BK 16
#define LDSA 68
#define LDSB 132

__global__ __launch_bounds__(256) void fb_encode_gemm(
    const float* __restrict__ x, const float* __restrict__ W_enc,
    const float* __restrict__ b_enc, float* __restrict__ out_acts)
{
    __shared__ float As[BK * LDSA];
    __shared__ float Bs[BK * LDSB];
    const int tid = threadIdx.x;
    const int nt = blockIdx.x, mt = blockIdx.y;
    const int g = nt >> 6, sbase = (nt & 63) * BN, mbase = mt * BM;
    const float* Bp = W_enc + ((size_t)g * D_MODEL) * SUB + sbase;
    const float* Ap = x + (size_t)mbase * D_MODEL;
    const int a_m = tid >> 2, a_c = (tid & 3) * 4;
    const int b_k = tid >> 5, b_c = (tid & 31) * 4;
    const int tr = tid >> 4, tc = tid & 15;
    float tot[4][8], cur[4][8];
#pragma unroll
    for (int i = 0; i < 4; ++i)
#pragma unroll
        for (int j = 0; j < 8; ++j) { tot[i][j] = 0.f; cur[i][j] = 0.f; }
#pragma unroll 1
    for (int it = 0; it < 64; ++it) {
        const int k0 = it * BK;
        const v4f va = *(const v4f*)(Ap + (size_t)a_m * D_MODEL + k0 + a_c);
        const v4f vb0 = *(const v4f*)(Bp + (size_t)(k0 + b_k) * SUB + b_c);
        const v4f vb1 = *(const v4f*)(Bp + (size_t)(k0 + b_k + 8) * SUB + b_c);
#pragma unroll
        for (int j = 0; j < 4; ++j) As[(a_c + j) * LDSA + a_m] = va[j];
        *(v4f*)&Bs[b_k * LDSB + b_c] = vb0;
        *(v4f*)&Bs[(b_k + 8) * LDSB + b_c] = vb1;
        __syncthreads();
        if (it == 24 || it == 48) {
#pragma unroll
            for (int i = 0; i < 4; ++i)
#pragma unroll
                for (int j = 0; j < 8; ++j) { tot[i][j] = __fadd_rn(tot[i][j], cur[i][j]); cur[i][j] = 0.f; }
        }
#pragma unroll
        for (int kk = 0; kk < BK; ++kk) {
            float a[4], bb[8];
            *(v4f*)&a[0] = *(const v4f*)&As[kk * LDSA + tr * 4];
            *(v4f*)&bb[0] = *(const v4f*)&Bs[kk * LDSB + tc * 4];
            *(v4f*)&bb[4] = *(const v4f*)&Bs[kk * LDSB + tc * 4 + 64];
#pragma unroll
            for (int i = 0; i < 4; ++i)
#pragma unroll
                for (int j = 0; j < 8; ++j) cur[i][j] = fmaf(a[i], bb[j], cur[i][j]);
        }
        __syncthreads();
    }
#pragma unroll
    for (int i = 0; i < 4; ++i)
#pragma unroll
        for (int j = 0; j < 8; ++j) tot[i][j] = __fadd_rn(tot[i][j], cur[i][j]);
    const float* bias = b_enc + (size_t)g * SUB + sbase;
    const float4 bb0 = *(const float4*)(bias + tc * 4);
    const float4 bb1 = *(const float4*)(bias + tc * 4 + 64);
    float* outp = out_acts + (size_t)g * SUB + sbase;
#pragma unroll
    for (int i = 0; i < 4; ++i) {
        const size_t row = (size_t)(mbase + tr * 4 + i);
        const float4 o0 = make_float4(__fadd_rn(tot[i][0], bb0.x), __fadd_rn(tot[i][1], bb0.y),
                                      __fadd_rn(tot[i][2], bb0.z), __fadd_rn(tot[i][3], bb0.w));
        const float4 o1 = make_float4(__fadd_rn(tot[i][4], bb1.x), __fadd_rn(tot[i][5], bb1.y),
                                      __fadd_rn(tot[i][6], bb1.z), __fadd_rn(tot[i][7], bb1.w));
        *(float4*)(outp + row * NTOT + tc * 4) = o0;
        *(float4*)(outp + row * NTOT + tc * 4 + 64) = o1;
    }
}

__global__ __launch_bounds__(256) void fb_topk_decode(
    const float* __restrict__ W_dec, float* __restrict__ out_recon,
    float* __restrict__ out_acts)
{
    __shared__ float row[SUB + (SUB >> 5)];
    __shared__ unsigned hist[256], sscan[256], wsum[4], wsum2[4];
    __shared__ unsigned sh_bin, sh_above;
    __shared__ int sel_idx[TOPK];
    __shared__ float sel_val[TOPK];
    const int tid = threadIdx.x, lane = tid & 63, w = tid >> 6;
    const size_t b = blockIdx.x;
    float r0 = 0.f, r1 = 0.f, r2 = 0.f, r3 = 0.f;
    for (int g = 0; g < NGROUPS; ++g) {
        float* rowg = out_acts + b * NTOT + (size_t)g * SUB;
#pragma unroll
        for (int t = 0; t < 8; ++t) {
            const int i4 = tid + t * 256;
            const float4 v = *(const float4*)(rowg + (size_t)i4 * 4);
            const int s0 = i4 * 4;
            row[PIDX(s0) + 0] = v.x; row[PIDX(s0) + 1] = v.y;
            row[PIDX(s0) + 2] = v.z; row[PIDX(s0) + 3] = v.w;
        }
        __syncthreads();
        unsigned prefix = 0, kwant = TOPK;
#pragma unroll
        for (int r = 0; r < 4; ++r) {
            const int shift = 24 - 8 * r;
            hist[tid] = 0;
            __syncthreads();
            for (int j = 0; j < 32; ++j) {
                const unsigned key = fkey(row[tid * 33 + j]);
                const unsigned hi = (unsigned)(((unsigned long long)key) >> (shift + 8));
                const unsigned pi = (unsigned)(((unsigned long long)prefix) >> (shift + 8));
                if (hi == pi) atomicAdd(&hist[(key >> shift) & 255u], 1u);
            }
            __syncthreads();
            unsigned s = hist[tid];
#pragma unroll
            for (int off = 1; off < 64; off <<= 1) {
                const unsigned o = __shfl_down(s, off, 64);
                if (lane + off < 64) s += o;
            }
            if (lane == 0) wsum[w] = s;
            __syncthreads();
            unsigned add = 0;
            for (int w2 = w + 1; w2 < 4; ++w2) add += wsum[w2];
            s += add;
            sscan[tid] = s;
            __syncthreads();
            const unsigned snext = (tid < 255) ? sscan[tid + 1] : 0u;
            if (s >= kwant && snext < kwant) { sh_bin = (unsigned)tid; sh_above = snext; }
            __syncthreads();
            prefix |= sh_bin << shift;
            kwant -= sh_above;
            __syncthreads();
        }
        const unsigned T = prefix, n_take = kwant, cnt_gt_total = TOPK - n_take;
        unsigned loc_gt = 0, loc_eq = 0;
        for (int j = 0; j < 32; ++j) {
            const unsigned key = fkey(row[tid * 33 + j]);
            loc_gt += (key > T); loc_eq += (key == T);
        }
        const unsigned pack = loc_gt | (loc_eq << 16);
        unsigned sI = pack;
#pragma unroll
        for (int off = 1; off < 64; off <<= 1) {
            const unsigned o = __shfl_up(sI, off, 64);
            if (lane >= off) sI += o;
        }
        if (lane == 63) wsum2[w] = sI;
        __syncthreads();
        unsigned woff = 0;
        for (int w2 = 0; w2 < w; ++w2) woff += wsum2[w2];
        const unsigned excl = sI - pack + woff;
        unsigned run_gt = excl & 0xFFFFu, run_eq = excl >> 16;
        for (int j = 0; j < 32; ++j) {
            const int sidx = tid * 32 + j;
            const float f = row[tid * 33 + j];
            const unsigned key = fkey(f);
            const float act = fmaxf(f, 0.f);
            if (key > T) { sel_idx[run_gt] = sidx; sel_val[run_gt] = act; ++run_gt; row[tid * 33 + j] = act; }
            else if (key == T) {
                if (run_eq < n_take) { sel_idx[cnt_gt_total + run_eq] = sidx; sel_val[cnt_gt_total + run_eq] = act; row[tid * 33 + j] = act; }
                else row[tid * 33 + j] = 0.f;
                ++run_eq;
            } else row[tid * 33 + j] = 0.f;
        }
        __syncthreads();
#pragma unroll
        for (int t = 0; t < 8; ++t) {
            const int i4 = tid + t * 256;
            const int s0 = i4 * 4;
            *(float4*)(rowg + (size_t)i4 * 4) =
                make_float4(row[PIDX(s0)], row[PIDX(s0) + 1], row[PIDX(s0) + 2], row[PIDX(s0) + 3]);
        }
        const float* Wg = W_dec + (size_t)g * SUB * D_MODEL + tid * 4;
#pragma unroll 8
        for (int j = 0; j < TOPK; ++j) {
            const float v = sel_val[j];
            const float4 wv = *(const float4*)(Wg + (size_t)sel_idx[j] * D_MODEL);
            r0 = fmaf(v, wv.x, r0); r1 = fmaf(v, wv.y, r1);
            r2 = fmaf(v, wv.z, r2); r3 = fmaf(v, wv.w, r3);
        }
        __syncthreads();
    }
    *(float4*)(out_recon + b * D_MODEL + tid * 4) = make_float4(r0, r1, r2, r3);
}

extern "C" void kernel_launch(void* const* d_in, const int* in_sizes, int n_in,
                              void* d_out, int out_size, void* d_ws, size_t ws_size,
                              hipStream_t stream) {
    const float* x     = (const float*)d_in[0];
    const float* W_enc = (const float*)d_in[1];
    const float* b_enc = (const float*)d_in[2];
    const float* W_dec = (const float*)d_in[3];

    float* out_recon = (float*)d_out;
    float* out_acts  = (float*)d_out + (size_t)BATCH * D_MODEL;

    const size_t WT_BYTES = (size_t)NGROUPS * SUB * D_MODEL * 4;   // 268 MB
    if (ws_size >= WT_BYTES) {
        float* WT = (float*)d_ws;
        transpose_wenc<<<dim3(SUB / 32, D_MODEL / 32, NGROUPS), 256, 0, stream>>>(W_enc, WT);
        mfma_scores<<<dim3(BATCH / 128, NTOT / 128), 256, 0, stream>>>(x, W_enc, b_enc, out_acts);
        select_decode<<<BATCH, 256, 0, stream>>>(x, WT, b_enc, W_dec, out_recon, out_acts);
    } else {
        fb_encode_gemm<<<dim3(NTOT / BN, BATCH / BM), 256, 0, stream>>>(x, W_enc, b_enc, out_acts);
        fb_topk_decode<<<BATCH, 256, 0, stream>>>(W_dec, out_recon, out_acts);
    }
}

// Round 11
// 1956.577 us; speedup vs baseline: 19.6184x; 1.9039x over previous
//
#include <hip/hip_runtime.h>

#define D_MODEL 1024
#define NGROUPS 8
#define SUB 8192
#define TOPK 32
#define BATCH 2048
#define NTOT (NGROUPS * SUB)   // 65536

typedef float v4f __attribute__((ext_vector_type(4)));
typedef _Float16 f16x8 __attribute__((ext_vector_type(8)));
typedef float f32x4 __attribute__((ext_vector_type(4)));

__device__ __forceinline__ unsigned fkey(float f) {
    unsigned u = __float_as_uint(f);
    return (u & 0x80000000u) ? ~u : (u | 0x80000000u);  // monotonic
}
__device__ __forceinline__ float inv_fkey(unsigned key) {
    unsigned u = (key & 0x80000000u) ? (key & 0x7FFFFFFFu) : ~key;
    return __uint_as_float(u);
}
__device__ __forceinline__ unsigned pack2h(float a, float b) {
    _Float16 ha = (_Float16)a, hb = (_Float16)b;
    return (unsigned)__builtin_bit_cast(unsigned short, ha)
         | ((unsigned)__builtin_bit_cast(unsigned short, hb) << 16);
}

// ================= k1: transpose W_enc [g][k][s] -> WT [g][s][k] =================
__global__ __launch_bounds__(256) void transpose_wenc(
    const float* __restrict__ W, float* __restrict__ WT)
{
    __shared__ float t[32][33];
    const int g = blockIdx.z, kt = blockIdx.y, st = blockIdx.x;
    const int lx = threadIdx.x & 31, ly = threadIdx.x >> 5;   // ly 0..7
    const float* Wg = W + (size_t)g * D_MODEL * SUB;
    float* WTg = WT + (size_t)g * SUB * D_MODEL;
#pragma unroll
    for (int r = 0; r < 4; ++r)
        t[ly + 8 * r][lx] = Wg[(size_t)(kt * 32 + ly + 8 * r) * SUB + st * 32 + lx];
    __syncthreads();
#pragma unroll
    for (int r = 0; r < 4; ++r)
        WTg[(size_t)(st * 32 + ly + 8 * r) * D_MODEL + kt * 32 + lx] = t[lx][ly + 8 * r];
}

// ================= k2: f16 MFMA approx scores = x @ W_enc + b_enc ================
__global__ __launch_bounds__(256) void mfma_scores(
    const float* __restrict__ x, const float* __restrict__ W_enc,
    const float* __restrict__ b_enc, float* __restrict__ scores)
{
    __shared__ _Float16 Ah[128 * 40];   // [m][k] stride 40
    __shared__ unsigned Bp[16 * 132];   // [k-pair][s] stride 132 (f16x2 packed)

    const int tid = threadIdx.x;
    const int mt = blockIdx.x, nt = blockIdx.y;   // mt fast => W-strip reuse in L2
    const int g = nt >> 6;
    const int sbase = (nt & 63) * 128;
    const int mbase = mt * 128;

    const float* Bg = W_enc + (size_t)g * D_MODEL * SUB + sbase;
    const int lane = tid & 63, w = tid >> 6;
    const int wm = w >> 1, wn = w & 1;
    const int l15 = lane & 15, grp = lane >> 4;

    const int am = tid >> 1, akh = (tid & 1) * 16;        // A staging
    const int bk4 = (tid >> 5) * 4, bs4 = (tid & 31) * 4; // B staging

    f32x4 acc[4][4];
#pragma unroll
    for (int i = 0; i < 4; ++i)
#pragma unroll
        for (int j = 0; j < 4; ++j) acc[i][j] = (f32x4){0.f, 0.f, 0.f, 0.f};

#pragma unroll 1
    for (int it = 0; it < 32; ++it) {
        const int k0 = it * 32;
        const float* ap = x + (size_t)(mbase + am) * D_MODEL + k0 + akh;
        const v4f a0 = *(const v4f*)(ap);
        const v4f a1 = *(const v4f*)(ap + 4);
        const v4f a2 = *(const v4f*)(ap + 8);
        const v4f a3 = *(const v4f*)(ap + 12);
        v4f br[4];
#pragma unroll
        for (int r = 0; r < 4; ++r)
            br[r] = *(const v4f*)(Bg + (size_t)(k0 + bk4 + r) * SUB + bs4);

        f16x8 v0, v1;
#pragma unroll
        for (int j = 0; j < 4; ++j) {
            v0[j] = (_Float16)a0[j]; v0[4 + j] = (_Float16)a1[j];
            v1[j] = (_Float16)a2[j]; v1[4 + j] = (_Float16)a3[j];
        }
        *(f16x8*)&Ah[am * 40 + akh]     = v0;
        *(f16x8*)&Ah[am * 40 + akh + 8] = v1;
        const int kp0 = bk4 >> 1;
        uint4 p0, p1;
        p0.x = pack2h(br[0][0], br[1][0]); p0.y = pack2h(br[0][1], br[1][1]);
        p0.z = pack2h(br[0][2], br[1][2]); p0.w = pack2h(br[0][3], br[1][3]);
        p1.x = pack2h(br[2][0], br[3][0]); p1.y = pack2h(br[2][1], br[3][1]);
        p1.z = pack2h(br[2][2], br[3][2]); p1.w = pack2h(br[2][3], br[3][3]);
        *(uint4*)&Bp[kp0 * 132 + bs4]       = p0;
        *(uint4*)&Bp[(kp0 + 1) * 132 + bs4] = p1;
        __syncthreads();

        f16x8 af[4], bf[4];
#pragma unroll
        for (int i = 0; i < 4; ++i)
            af[i] = *(const f16x8*)&Ah[(wm * 64 + i * 16 + l15) * 40 + 8 * grp];
#pragma unroll
        for (int j = 0; j < 4; ++j) {
            const int col = wn * 64 + j * 16 + l15;
            uint4 q;
            q.x = Bp[(4 * grp + 0) * 132 + col];
            q.y = Bp[(4 * grp + 1) * 132 + col];
            q.z = Bp[(4 * grp + 2) * 132 + col];
            q.w = Bp[(4 * grp + 3) * 132 + col];
            bf[j] = __builtin_bit_cast(f16x8, q);
        }
#pragma unroll
        for (int i = 0; i < 4; ++i)
#pragma unroll
            for (int j = 0; j < 4; ++j)
                acc[i][j] = __builtin_amdgcn_mfma_f32_16x16x32_f16(af[i], bf[j], acc[i][j], 0, 0, 0);
        __syncthreads();
    }

    float bb[4];
#pragma unroll
    for (int j = 0; j < 4; ++j)
        bb[j] = b_enc[(size_t)g * SUB + sbase + wn * 64 + j * 16 + l15];
#pragma unroll
    for (int i = 0; i < 4; ++i) {
        const int row = mbase + wm * 64 + i * 16 + grp * 4;
#pragma unroll
        for (int j = 0; j < 4; ++j) {
            const size_t col = (size_t)g * SUB + sbase + wn * 64 + j * 16 + l15;
#pragma unroll
            for (int r = 0; r < 4; ++r)
                scores[(size_t)(row + r) * NTOT + col] = __fadd_rn(acc[i][j][r], bb[j]);
        }
    }
}

// ================= k3: select + parallel exact recompute + decode =================
// Phase 1: per group radix-select approx v32; append candidates (approx >= v32-0.06,
//          margin >= 2*delta, delta<=0.025 f16 bound) to block list; zero row.
// Phase 2: ONE CANDIDATE PER LANE, all groups at once: stream WT column from global
//          (float4), three interleaved BLAS chains P0/P1/P2 (k ascending per chunk),
//          fold ((P0+P1)+P2)+bias with rounded adds — bit-identical arithmetic order.
// Phase 3: per group: exact rank (val desc, feature-idx asc), scatter, decode.
#define PIDX(s) ((s) + ((s) >> 5))
#define CTOT 1024

__global__ __launch_bounds__(256) void select_decode(
    const float* __restrict__ x, const float* __restrict__ WT,
    const float* __restrict__ b_enc, const float* __restrict__ W_dec,
    float* __restrict__ out_recon, float* __restrict__ out_acts)
{
    __shared__ float pool[8448];
    __shared__ float xrow[1024];
    __shared__ unsigned hist[256], sscan[256], wsum[4];
    __shared__ unsigned sh_bin, sh_above, cand_cnt;
    __shared__ int   cidx[CTOT];      // (g<<13)|sidx
    __shared__ float cval[CTOT];
    __shared__ int   gend[NGROUPS];
    __shared__ int   sel_idx[TOPK];
    __shared__ float sel_val[TOPK];

    const int tid = threadIdx.x;
    const int lane = tid & 63;
    const int w = tid >> 6;
    const size_t b = blockIdx.x;

    *(float4*)&xrow[tid * 4] = *(const float4*)(x + b * D_MODEL + tid * 4);
    if (tid == 0) cand_cnt = 0;
    float r0 = 0.f, r1 = 0.f, r2 = 0.f, r3 = 0.f;

    // ---------------- Phase 1: per-group select + append + zero ----------------
    for (int g = 0; g < NGROUPS; ++g) {
        float* rowg = out_acts + b * NTOT + (size_t)g * SUB;
#pragma unroll
        for (int t = 0; t < 8; ++t) {
            const int i4 = tid + t * 256;
            const float4 v = *(const float4*)(rowg + (size_t)i4 * 4);
            const int s0 = i4 * 4;
            pool[PIDX(s0) + 0] = v.x; pool[PIDX(s0) + 1] = v.y;
            pool[PIDX(s0) + 2] = v.z; pool[PIDX(s0) + 3] = v.w;
        }
        __syncthreads();

        unsigned prefix = 0, kwant = TOPK;
#pragma unroll
        for (int r = 0; r < 4; ++r) {
            const int shift = 24 - 8 * r;
            hist[tid] = 0;
            __syncthreads();
            for (int j = 0; j < 32; ++j) {
                const unsigned key = fkey(pool[tid * 33 + j]);
                const unsigned hi = (unsigned)(((unsigned long long)key) >> (shift + 8));
                const unsigned pi = (unsigned)(((unsigned long long)prefix) >> (shift + 8));
                if (hi == pi) atomicAdd(&hist[(key >> shift) & 255u], 1u);
            }
            __syncthreads();
            unsigned s = hist[tid];
#pragma unroll
            for (int off = 1; off < 64; off <<= 1) {
                const unsigned o = __shfl_down(s, off, 64);
                if (lane + off < 64) s += o;
            }
            if (lane == 0) wsum[w] = s;
            __syncthreads();
            unsigned add = 0;
            for (int w2 = w + 1; w2 < 4; ++w2) add += wsum[w2];
            s += add;
            sscan[tid] = s;
            __syncthreads();
            const unsigned snext = (tid < 255) ? sscan[tid + 1] : 0u;
            if (s >= kwant && snext < kwant) { sh_bin = (unsigned)tid; sh_above = snext; }
            __syncthreads();
            prefix |= sh_bin << shift;
            kwant -= sh_above;
            __syncthreads();
        }
        const unsigned wkey = fkey(inv_fkey(prefix) - 0.06f);

        for (int j = 0; j < 32; ++j) {
            const float f = pool[tid * 33 + j];
            if (fkey(f) >= wkey) {
                const unsigned slot = atomicAdd(&cand_cnt, 1u);
                if (slot < CTOT) cidx[slot] = (g << 13) | (tid * 32 + j);
            }
        }
#pragma unroll
        for (int t = 0; t < 8; ++t)
            *(float4*)(rowg + (size_t)(tid + t * 256) * 4) = make_float4(0.f, 0.f, 0.f, 0.f);
        __syncthreads();
        if (tid == 0) gend[g] = (int)min(cand_cnt, (unsigned)CTOT);
        __syncthreads();
    }

    // ---------------- Phase 2: one candidate per lane, BLAS-exact chains ----------------
    const int cnt = gend[NGROUPS - 1];
    for (int base = 0; base < cnt; base += 256) {
        const int c = base + tid;
        if (c < cnt) {
            const int id = cidx[c];
            const int g = id >> 13, sidx = id & 8191;
            const float* col = WT + ((size_t)g * SUB + sidx) * D_MODEL;
            float a0 = 0.f, a1 = 0.f, a2 = 0.f;
#pragma unroll 4
            for (int q = 0; q < 64; ++q) {
                const float4 w0 = *(const float4*)(col + q * 4);
                const float4 w1 = *(const float4*)(col + 384 + q * 4);
                const float4 w2 = *(const float4*)(col + 768 + q * 4);
                a0 = fmaf(xrow[q * 4 + 0], w0.x, a0); a1 = fmaf(xrow[384 + q * 4 + 0], w1.x, a1); a2 = fmaf(xrow[768 + q * 4 + 0], w2.x, a2);
                a0 = fmaf(xrow[q * 4 + 1], w0.y, a0); a1 = fmaf(xrow[384 + q * 4 + 1], w1.y, a1); a2 = fmaf(xrow[768 + q * 4 + 1], w2.y, a2);
                a0 = fmaf(xrow[q * 4 + 2], w0.z, a0); a1 = fmaf(xrow[384 + q * 4 + 2], w1.z, a1); a2 = fmaf(xrow[768 + q * 4 + 2], w2.z, a2);
                a0 = fmaf(xrow[q * 4 + 3], w0.w, a0); a1 = fmaf(xrow[384 + q * 4 + 3], w1.w, a1); a2 = fmaf(xrow[768 + q * 4 + 3], w2.w, a2);
            }
#pragma unroll 4
            for (int q = 64; q < 96; ++q) {
                const float4 w0 = *(const float4*)(col + q * 4);
                const float4 w1 = *(const float4*)(col + 384 + q * 4);
                a0 = fmaf(xrow[q * 4 + 0], w0.x, a0); a1 = fmaf(xrow[384 + q * 4 + 0], w1.x, a1);
                a0 = fmaf(xrow[q * 4 + 1], w0.y, a0); a1 = fmaf(xrow[384 + q * 4 + 1], w1.y, a1);
                a0 = fmaf(xrow[q * 4 + 2], w0.z, a0); a1 = fmaf(xrow[384 + q * 4 + 2], w1.z, a1);
                a0 = fmaf(xrow[q * 4 + 3], w0.w, a0); a1 = fmaf(xrow[384 + q * 4 + 3], w1.w, a1);
            }
            cval[c] = __fadd_rn(__fadd_rn(__fadd_rn(a0, a1), a2),
                                b_enc[(size_t)g * SUB + sidx]);
        }
    }
    __syncthreads();

    // ---------------- Phase 3: per-group exact rank + scatter + decode ----------------
    for (int g = 0; g < NGROUPS; ++g) {
        const int gb = (g == 0) ? 0 : gend[g - 1];
        const int ge = gend[g];
        for (int t = gb + tid; t < ge; t += 256) {
            const unsigned mykey = fkey(cval[t]);
            const int mys = cidx[t] & 8191;
            int rank = 0;
            for (int e = gb; e < ge; ++e) {
                const unsigned ke = fkey(cval[e]);
                if (ke > mykey || (ke == mykey && (cidx[e] & 8191) < mys)) ++rank;
            }
            if (rank < TOPK) { sel_idx[rank] = mys; sel_val[rank] = fmaxf(cval[t], 0.f); }
        }
        __syncthreads();

        float* rowg = out_acts + b * NTOT + (size_t)g * SUB;
        if (tid < TOPK) rowg[sel_idx[tid]] = sel_val[tid];

        const float* Wg = W_dec + (size_t)g * SUB * D_MODEL + tid * 4;
#pragma unroll 8
        for (int j = 0; j < TOPK; ++j) {
            const float v = sel_val[j];
            const float4 wv = *(const float4*)(Wg + (size_t)sel_idx[j] * D_MODEL);
            r0 = fmaf(v, wv.x, r0); r1 = fmaf(v, wv.y, r1);
            r2 = fmaf(v, wv.z, r2); r3 = fmaf(v, wv.w, r3);
        }
        __syncthreads();
    }
    *(float4*)(out_recon + b * D_MODEL + tid * 4) = make_float4(r0, r1, r2, r3);
}

// ================= Fallback: R5 exact fp32 path (if ws too small) =================
#define BM 64
#define BN 128
#define BK 16
#define LDSA 68
#define LDSB 132

__global__ __launch_bounds__(256) void fb_encode_gemm(
    const float* __restrict__ x, const float* __restrict__ W_enc,
    const float* __restrict__ b_enc, float* __restrict__ out_acts)
{
    __shared__ float As[BK * LDSA];
    __shared__ float Bs[BK * LDSB];
    const int tid = threadIdx.x;
    const int nt = blockIdx.x, mt = blockIdx.y;
    const int g = nt >> 6, sbase = (nt & 63) * BN, mbase = mt * BM;
    const float* Bp = W_enc + ((size_t)g * D_MODEL) * SUB + sbase;
    const float* Ap = x + (size_t)mbase * D_MODEL;
    const int a_m = tid >> 2, a_c = (tid & 3) * 4;
    const int b_k = tid >> 5, b_c = (tid & 31) * 4;
    const int tr = tid >> 4, tc = tid & 15;
    float tot[4][8], cur[4][8];
#pragma unroll
    for (int i = 0; i < 4; ++i)
#pragma unroll
        for (int j = 0; j < 8; ++j) { tot[i][j] = 0.f; cur[i][j] = 0.f; }
#pragma unroll 1
    for (int it = 0; it < 64; ++it) {
        const int k0 = it * BK;
        const v4f va = *(const v4f*)(Ap + (size_t)a_m * D_MODEL + k0 + a_c);
        const v4f vb0 = *(const v4f*)(Bp + (size_t)(k0 + b_k) * SUB + b_c);
        const v4f vb1 = *(const v4f*)(Bp + (size_t)(k0 + b_k + 8) * SUB + b_c);
#pragma unroll
        for (int j = 0; j < 4; ++j) As[(a_c + j) * LDSA + a_m] = va[j];
        *(v4f*)&Bs[b_k * LDSB + b_c] = vb0;
        *(v4f*)&Bs[(b_k + 8) * LDSB + b_c] = vb1;
        __syncthreads();
        if (it == 24 || it == 48) {
#pragma unroll
            for (int i = 0; i < 4; ++i)
#pragma unroll
                for (int j = 0; j < 8; ++j) { tot[i][j] = __fadd_rn(tot[i][j], cur[i][j]); cur[i][j] = 0.f; }
        }
#pragma unroll
        for (int kk = 0; kk < BK; ++kk) {
            float a[4], bb[8];
            *(v4f*)&a[0] = *(const v4f*)&As[kk * LDSA + tr * 4];
            *(v4f*)&bb[0] = *(const v4f*)&Bs[kk * LDSB + tc * 4];
            *(v4f*)&bb[4] = *(const v4f*)&Bs[kk * LDSB + tc * 4 + 64];
#pragma unroll
            for (int i = 0; i < 4; ++i)
#pragma unroll
                for (int j = 0; j < 8; ++j) cur[i][j] = fmaf(a[i], bb[j], cur[i][j]);
        }
        __syncthreads();
    }
#pragma unroll
    for (int i = 0; i < 4; ++i)
#pragma unroll
        for (int j = 0; j < 8; ++j) tot[i][j] = __fadd_rn(tot[i][j], cur[i][j]);
    const float* bias = b_enc + (size_t)g * SUB + sbase;
    const float4 bb0 = *(const float4*)(bias + tc * 4);
    const float4 bb1 = *(const float4*)(bias + tc * 4 + 64);
    float* outp = out_acts + (size_t)g * SUB + sbase;
#pragma unroll
    for (int i = 0; i < 4; ++i) {
        const size_t row = (size_t)(mbase + tr * 4 + i);
        const float4 o0 = make_float4(__fadd_rn(tot[i][0], bb0.x), __fadd_rn(tot[i][1], bb0.y),
                                      __fadd_rn(tot[i][2], bb0.z), __fadd_rn(tot[i][3], bb0.w));
        const float4 o1 = make_float4(__fadd_rn(tot[i][4], bb1.x), __fadd_rn(tot[i][5], bb1.y),
                                      __fadd_rn(tot[i][6], bb1.z), __fadd_rn(tot[i][7], bb1.w));
        *(float4*)(outp + row * NTOT + tc * 4) = o0;
        *(float4*)(outp + row * NTOT + tc * 4 + 64) = o1;
    }
}

__global__ __launch_bounds__(256) void fb_topk_decode(
    const float* __restrict__ W_dec, float* __restrict__ out_recon,
    float* __restrict__ out_acts)
{
    __shared__ float row[SUB + (SUB >> 5)];
    __shared__ unsigned hist[256], sscan[256], wsum[4], wsum2[4];
    __shared__ unsigned sh_bin, sh_above;
    __shared__ int sel_idx[TOPK];
    __shared__ float sel_val[TOPK];
    const int tid = threadIdx.x, lane = tid & 63, w = tid >> 6;
    const size_t b = blockIdx.x;
    float r0 = 0.f, r1 = 0.f, r2 = 0.f, r3 = 0.f;
    for (int g = 0; g < NGROUPS; ++g) {
        float* rowg = out_acts + b * NTOT + (size_t)g * SUB;
#pragma unroll
        for (int t = 0; t < 8; ++t) {
            const int i4 = tid + t * 256;
            const float4 v = *(const float4*)(rowg + (size_t)i4 * 4);
            const int s0 = i4 * 4;
            row[PIDX(s0) + 0] = v.x; row[PIDX(s0) + 1] = v.y;
            row[PIDX(s0) + 2] = v.z; row[PIDX(s0) + 3] = v.w;
        }
        __syncthreads();
        unsigned prefix = 0, kwant = TOPK;
#pragma unroll
        for (int r = 0; r < 4; ++r) {
            const int shift = 24 - 8 * r;
            hist[tid] = 0;
            __syncthreads();
            for (int j = 0; j < 32; ++j) {
                const unsigned key = fkey(row[tid * 33 + j]);
                const unsigned hi = (unsigned)(((unsigned long long)key) >> (shift + 8));
                const unsigned pi = (unsigned)(((unsigned long long)prefix) >> (shift + 8));
                if (hi == pi) atomicAdd(&hist[(key >> shift) & 255u], 1u);
            }
            __syncthreads();
            unsigned s = hist[tid];
#pragma unroll
            for (int off = 1; off < 64; off <<= 1) {
                const unsigned o = __shfl_down(s, off, 64);
                if (lane + off < 64) s += o;
            }
            if (lane == 0) wsum[w] = s;
            __syncthreads();
            unsigned add = 0;
            for (int w2 = w + 1; w2 < 4; ++w2) add += wsum[w2];
            s += add;
            sscan[tid] = s;
            __syncthreads();
            const unsigned snext = (tid < 255) ? sscan[tid + 1] : 0u;
            if (s >= kwant && snext < kwant) { sh_bin = (unsigned)tid; sh_above = snext; }
            __syncthreads();
            prefix |= sh_bin << shift;
            kwant -= sh_above;
            __syncthreads();
        }
        const unsigned T = prefix, n_take = kwant, cnt_gt_total = TOPK - n_take;
        unsigned loc_gt = 0, loc_eq = 0;
        for (int j = 0; j < 32; ++j) {
            const unsigned key = fkey(row[tid * 33 + j]);
            loc_gt += (key > T); loc_eq += (key == T);
        }
        const unsigned pack = loc_gt | (loc_eq << 16);
        unsigned sI = pack;
#pragma unroll
        for (int off = 1; off < 64; off <<= 1) {
            const unsigned o = __shfl_up(sI, off, 64);
            if (lane >= off) sI += o;
        }
        if (lane == 63) wsum2[w] = sI;
        __syncthreads();
        unsigned woff = 0;
        for (int w2 = 0; w2 < w; ++w2) woff += wsum2[w2];
        const unsigned excl = sI - pack + woff;
        unsigned run_gt = excl & 0xFFFFu, run_eq = excl >> 16;
        for (int j = 0; j < 32; ++j) {
            const int sidx = tid * 32 + j;
            const float f = row[tid * 33 + j];
            const unsigned key = fkey(f);
            const float act = fmaxf(f, 0.f);
            if (key > T) { sel_idx[run_gt] = sidx; sel_val[run_gt] = act; ++run_gt; row[tid * 33 + j] = act; }
            else if (key == T) {
                if (run_eq < n_take) { sel_idx[cnt_gt_total + run_eq] = sidx; sel_val[cnt_gt_total + run_eq] = act; row[tid * 33 + j] = act; }
                else row[tid * 33 + j] = 0.f;
                ++run_eq;
            } else row[tid * 33 + j] = 0.f;
        }
        __syncthreads();
#pragma unroll
        for (int t = 0; t < 8; ++t) {
            const int i4 = tid + t * 256;
            const int s0 = i4 * 4;
            *(float4*)(rowg + (size_t)i4 * 4) =
                make_float4(row[PIDX(s0)], row[PIDX(s0) + 1], row[PIDX(s0) + 2], row[PIDX(s0) + 3]);
        }
        const float* Wg = W_dec + (size_t)g * SUB * D_MODEL + tid * 4;
#pragma unroll 8
        for (int j = 0; j < TOPK; ++j) {
            const float v = sel_val[j];
            const float4 wv = *(const float4*)(Wg + (size_t)sel_idx[j] * D_MODEL);
            r0 = fmaf(v, wv.x, r0); r1 = fmaf(v, wv.y, r1);
            r2 = fmaf(v, wv.z, r2); r3 = fmaf(v, wv.w, r3);
        }
        __syncthreads();
    }
    *(float4*)(out_recon + b * D_MODEL + tid * 4) = make_float4(r0, r1, r2, r3);
}

extern "C" void kernel_launch(void* const* d_in, const int* in_sizes, int n_in,
                              void* d_out, int out_size, void* d_ws, size_t ws_size,
                              hipStream_t stream) {
    const float* x     = (const float*)d_in[0];
    const float* W_enc = (const float*)d_in[1];
    const float* b_enc = (const float*)d_in[2];
    const float* W_dec = (const float*)d_in[3];

    float* out_recon = (float*)d_out;
    float* out_acts  = (float*)d_out + (size_t)BATCH * D_MODEL;

    const size_t WT_BYTES = (size_t)NGROUPS * SUB * D_MODEL * 4;   // 268 MB
    if (ws_size >= WT_BYTES) {
        float* WT = (float*)d_ws;
        transpose_wenc<<<dim3(SUB / 32, D_MODEL / 32, NGROUPS), 256, 0, stream>>>(W_enc, WT);
        mfma_scores<<<dim3(BATCH / 128, NTOT / 128), 256, 0, stream>>>(x, W_enc, b_enc, out_acts);
        select_decode<<<BATCH, 256, 0, stream>>>(x, WT, b_enc, W_dec, out_recon, out_acts);
    } else {
        fb_encode_gemm<<<dim3(NTOT / BN, BATCH / BM), 256, 0, stream>>>(x, W_enc, b_enc, out_acts);
        fb_topk_decode<<<BATCH, 256, 0, stream>>>(W_dec, out_recon, out_acts);
    }
}

// Round 12
// 1742.699 us; speedup vs baseline: 22.0262x; 1.1227x over previous
//
#include <hip/hip_runtime.h>

#define D_MODEL 1024
#define NGROUPS 8
#define SUB 8192
#define TOPK 32
#define BATCH 2048
#define NTOT (NGROUPS * SUB)   // 65536

typedef float v4f __attribute__((ext_vector_type(4)));
typedef _Float16 f16x8 __attribute__((ext_vector_type(8)));
typedef float f32x4 __attribute__((ext_vector_type(4)));

__device__ __forceinline__ unsigned fkey(float f) {
    unsigned u = __float_as_uint(f);
    return (u & 0x80000000u) ? ~u : (u | 0x80000000u);  // monotonic
}
__device__ __forceinline__ float inv_fkey(unsigned key) {
    unsigned u = (key & 0x80000000u) ? (key & 0x7FFFFFFFu) : ~key;
    return __uint_as_float(u);
}
__device__ __forceinline__ unsigned pack2h(float a, float b) {
    _Float16 ha = (_Float16)a, hb = (_Float16)b;
    return (unsigned)__builtin_bit_cast(unsigned short, ha)
         | ((unsigned)__builtin_bit_cast(unsigned short, hb) << 16);
}

// ================= k1: transpose W_enc [g][k][s] -> WT [g][s][k] =================
__global__ __launch_bounds__(256) void transpose_wenc(
    const float* __restrict__ W, float* __restrict__ WT)
{
    __shared__ float t[32][33];
    const int g = blockIdx.z, kt = blockIdx.y, st = blockIdx.x;
    const int lx = threadIdx.x & 31, ly = threadIdx.x >> 5;   // ly 0..7
    const float* Wg = W + (size_t)g * D_MODEL * SUB;
    float* WTg = WT + (size_t)g * SUB * D_MODEL;
#pragma unroll
    for (int r = 0; r < 4; ++r)
        t[ly + 8 * r][lx] = Wg[(size_t)(kt * 32 + ly + 8 * r) * SUB + st * 32 + lx];
    __syncthreads();
#pragma unroll
    for (int r = 0; r < 4; ++r)
        WTg[(size_t)(st * 32 + ly + 8 * r) * D_MODEL + kt * 32 + lx] = t[lx][ly + 8 * r];
}

// ================= k2: f16 MFMA approx scores = x @ W_enc + b_enc ================
__global__ __launch_bounds__(256) void mfma_scores(
    const float* __restrict__ x, const float* __restrict__ W_enc,
    const float* __restrict__ b_enc, float* __restrict__ scores)
{
    __shared__ _Float16 Ah[128 * 40];   // [m][k] stride 40
    __shared__ unsigned Bp[16 * 132];   // [k-pair][s] stride 132 (f16x2 packed)

    const int tid = threadIdx.x;
    const int mt = blockIdx.x, nt = blockIdx.y;   // mt fast => W-strip reuse in L2
    const int g = nt >> 6;
    const int sbase = (nt & 63) * 128;
    const int mbase = mt * 128;

    const float* Bg = W_enc + (size_t)g * D_MODEL * SUB + sbase;
    const int lane = tid & 63, w = tid >> 6;
    const int wm = w >> 1, wn = w & 1;
    const int l15 = lane & 15, grp = lane >> 4;

    const int am = tid >> 1, akh = (tid & 1) * 16;        // A staging
    const int bk4 = (tid >> 5) * 4, bs4 = (tid & 31) * 4; // B staging

    f32x4 acc[4][4];
#pragma unroll
    for (int i = 0; i < 4; ++i)
#pragma unroll
        for (int j = 0; j < 4; ++j) acc[i][j] = (f32x4){0.f, 0.f, 0.f, 0.f};

#pragma unroll 1
    for (int it = 0; it < 32; ++it) {
        const int k0 = it * 32;
        const float* ap = x + (size_t)(mbase + am) * D_MODEL + k0 + akh;
        const v4f a0 = *(const v4f*)(ap);
        const v4f a1 = *(const v4f*)(ap + 4);
        const v4f a2 = *(const v4f*)(ap + 8);
        const v4f a3 = *(const v4f*)(ap + 12);
        v4f br[4];
#pragma unroll
        for (int r = 0; r < 4; ++r)
            br[r] = *(const v4f*)(Bg + (size_t)(k0 + bk4 + r) * SUB + bs4);

        f16x8 v0, v1;
#pragma unroll
        for (int j = 0; j < 4; ++j) {
            v0[j] = (_Float16)a0[j]; v0[4 + j] = (_Float16)a1[j];
            v1[j] = (_Float16)a2[j]; v1[4 + j] = (_Float16)a3[j];
        }
        *(f16x8*)&Ah[am * 40 + akh]     = v0;
        *(f16x8*)&Ah[am * 40 + akh + 8] = v1;
        const int kp0 = bk4 >> 1;
        uint4 p0, p1;
        p0.x = pack2h(br[0][0], br[1][0]); p0.y = pack2h(br[0][1], br[1][1]);
        p0.z = pack2h(br[0][2], br[1][2]); p0.w = pack2h(br[0][3], br[1][3]);
        p1.x = pack2h(br[2][0], br[3][0]); p1.y = pack2h(br[2][1], br[3][1]);
        p1.z = pack2h(br[2][2], br[3][2]); p1.w = pack2h(br[2][3], br[3][3]);
        *(uint4*)&Bp[kp0 * 132 + bs4]       = p0;
        *(uint4*)&Bp[(kp0 + 1) * 132 + bs4] = p1;
        __syncthreads();

        f16x8 af[4], bf[4];
#pragma unroll
        for (int i = 0; i < 4; ++i)
            af[i] = *(const f16x8*)&Ah[(wm * 64 + i * 16 + l15) * 40 + 8 * grp];
#pragma unroll
        for (int j = 0; j < 4; ++j) {
            const int col = wn * 64 + j * 16 + l15;
            uint4 q;
            q.x = Bp[(4 * grp + 0) * 132 + col];
            q.y = Bp[(4 * grp + 1) * 132 + col];
            q.z = Bp[(4 * grp + 2) * 132 + col];
            q.w = Bp[(4 * grp + 3) * 132 + col];
            bf[j] = __builtin_bit_cast(f16x8, q);
        }
#pragma unroll
        for (int i = 0; i < 4; ++i)
#pragma unroll
            for (int j = 0; j < 4; ++j)
                acc[i][j] = __builtin_amdgcn_mfma_f32_16x16x32_f16(af[i], bf[j], acc[i][j], 0, 0, 0);
        __syncthreads();
    }

    float bb[4];
#pragma unroll
    for (int j = 0; j < 4; ++j)
        bb[j] = b_enc[(size_t)g * SUB + sbase + wn * 64 + j * 16 + l15];
#pragma unroll
    for (int i = 0; i < 4; ++i) {
        const int row = mbase + wm * 64 + i * 16 + grp * 4;
#pragma unroll
        for (int j = 0; j < 4; ++j) {
            const size_t col = (size_t)g * SUB + sbase + wn * 64 + j * 16 + l15;
#pragma unroll
            for (int r = 0; r < 4; ++r)
                scores[(size_t)(row + r) * NTOT + col] = __fadd_rn(acc[i][j][r], bb[j]);
        }
    }
}

// ================= k3: select + parallel exact recompute + decode =================
// Phase 1 (per group): scores held in REGISTERS (32/thread); 2-round radix gives a
//   16-bit floor of the 32nd value (inv_fkey(prefix) <= v32); candidates =
//   approx >= floor - 0.06 (margin >= 2*delta, delta<=0.025 f16 bound) => superset
//   of the true top-32. Zero the row.
// Phase 2: one candidate per lane across ALL groups: stream WT column (float4),
//   three interleaved BLAS chains P0/P1/P2 (k ascending), fold ((P0+P1)+P2)+bias
//   with rounded adds — bit-identical BLAS arithmetic order.
// Phase 3 (per group): exact rank (val desc, feature-idx asc), scatter, decode.
#define CTOT 1024

__global__ __launch_bounds__(256) void select_decode(
    const float* __restrict__ x, const float* __restrict__ WT,
    const float* __restrict__ b_enc, const float* __restrict__ W_dec,
    float* __restrict__ out_recon, float* __restrict__ out_acts)
{
    __shared__ float xrow[1024];
    __shared__ unsigned hist[256], sscan[256], wsum[4];
    __shared__ unsigned sh_bin, sh_above, cand_cnt;
    __shared__ int   cidx[CTOT];      // (g<<13)|sidx
    __shared__ float cval[CTOT];
    __shared__ int   gend[NGROUPS];
    __shared__ int   sel_idx[TOPK];
    __shared__ float sel_val[TOPK];

    const int tid = threadIdx.x;
    const int lane = tid & 63;
    const int w = tid >> 6;
    const size_t b = blockIdx.x;

    *(float4*)&xrow[tid * 4] = *(const float4*)(x + b * D_MODEL + tid * 4);
    if (tid == 0) cand_cnt = 0;
    float r0 = 0.f, r1 = 0.f, r2 = 0.f, r3 = 0.f;

    // ---------------- Phase 1: per-group select + append + zero ----------------
    for (int g = 0; g < NGROUPS; ++g) {
        float* rowg = out_acts + b * NTOT + (size_t)g * SUB;

        // scores into registers (statically indexed)
        float sc[32];
#pragma unroll
        for (int t = 0; t < 8; ++t)
            *(v4f*)&sc[t * 4] = *(const v4f*)(rowg + (size_t)(tid + t * 256) * 4);

        // round 1: histogram of key>>24
        hist[tid] = 0;
        __syncthreads();
#pragma unroll
        for (int j = 0; j < 32; ++j)
            atomicAdd(&hist[fkey(sc[j]) >> 24], 1u);
        __syncthreads();

        unsigned prefix = 0, kwant = TOPK;
#pragma unroll
        for (int r = 0; r < 2; ++r) {
            // suffix scan over bins; find bin where count crosses kwant
            unsigned s = hist[tid];
#pragma unroll
            for (int off = 1; off < 64; off <<= 1) {
                const unsigned o = __shfl_down(s, off, 64);
                if (lane + off < 64) s += o;
            }
            if (lane == 0) wsum[w] = s;
            __syncthreads();
            unsigned add = 0;
            for (int w2 = w + 1; w2 < 4; ++w2) add += wsum[w2];
            s += add;
            sscan[tid] = s;
            __syncthreads();
            const unsigned snext = (tid < 255) ? sscan[tid + 1] : 0u;
            if (s >= kwant && snext < kwant) { sh_bin = (unsigned)tid; sh_above = snext; }
            __syncthreads();
            const int shift = 24 - 8 * r;
            prefix |= sh_bin << shift;
            kwant -= sh_above;
            __syncthreads();
            if (r == 0) {
                // round 2 histogram: (key>>16)&255 among keys matching top byte
                hist[tid] = 0;
                __syncthreads();
#pragma unroll
                for (int j = 0; j < 32; ++j) {
                    const unsigned key = fkey(sc[j]);
                    if ((key >> 24) == (prefix >> 24))
                        atomicAdd(&hist[(key >> 16) & 255u], 1u);
                }
                __syncthreads();
            }
        }
        // 16-bit floor of v32: inv_fkey(prefix) <= v32  => threshold is conservative
        const unsigned wkey = fkey(inv_fkey(prefix) - 0.06f);

#pragma unroll
        for (int j = 0; j < 32; ++j) {
            if (fkey(sc[j]) >= wkey) {
                const int sidx = (tid + (j >> 2) * 256) * 4 + (j & 3);
                const unsigned slot = atomicAdd(&cand_cnt, 1u);
                if (slot < CTOT) cidx[slot] = (g << 13) | sidx;
            }
        }
        // zero the output row
#pragma unroll
        for (int t = 0; t < 8; ++t)
            *(float4*)(rowg + (size_t)(tid + t * 256) * 4) = make_float4(0.f, 0.f, 0.f, 0.f);
        __syncthreads();
        if (tid == 0) gend[g] = (int)min(cand_cnt, (unsigned)CTOT);
        __syncthreads();
    }

    // ---------------- Phase 2: one candidate per lane, BLAS-exact chains ----------------
    const int cnt = gend[NGROUPS - 1];
    for (int base = 0; base < cnt; base += 256) {
        const int c = base + tid;
        if (c < cnt) {
            const int id = cidx[c];
            const int g = id >> 13, sidx = id & 8191;
            const float* col = WT + ((size_t)g * SUB + sidx) * D_MODEL;
            float a0 = 0.f, a1 = 0.f, a2 = 0.f;
#pragma unroll 4
            for (int q = 0; q < 64; ++q) {
                const float4 w0 = *(const float4*)(col + q * 4);
                const float4 w1 = *(const float4*)(col + 384 + q * 4);
                const float4 w2 = *(const float4*)(col + 768 + q * 4);
                a0 = fmaf(xrow[q * 4 + 0], w0.x, a0); a1 = fmaf(xrow[384 + q * 4 + 0], w1.x, a1); a2 = fmaf(xrow[768 + q * 4 + 0], w2.x, a2);
                a0 = fmaf(xrow[q * 4 + 1], w0.y, a0); a1 = fmaf(xrow[384 + q * 4 + 1], w1.y, a1); a2 = fmaf(xrow[768 + q * 4 + 1], w2.y, a2);
                a0 = fmaf(xrow[q * 4 + 2], w0.z, a0); a1 = fmaf(xrow[384 + q * 4 + 2], w1.z, a1); a2 = fmaf(xrow[768 + q * 4 + 2], w2.z, a2);
                a0 = fmaf(xrow[q * 4 + 3], w0.w, a0); a1 = fmaf(xrow[384 + q * 4 + 3], w1.w, a1); a2 = fmaf(xrow[768 + q * 4 + 3], w2.w, a2);
            }
#pragma unroll 4
            for (int q = 64; q < 96; ++q) {
                const float4 w0 = *(const float4*)(col + q * 4);
                const float4 w1 = *(const float4*)(col + 384 + q * 4);
                a0 = fmaf(xrow[q * 4 + 0], w0.x, a0); a1 = fmaf(xrow[384 + q * 4 + 0], w1.x, a1);
                a0 = fmaf(xrow[q * 4 + 1], w0.y, a0); a1 = fmaf(xrow[384 + q * 4 + 1], w1.y, a1);
                a0 = fmaf(xrow[q * 4 + 2], w0.z, a0); a1 = fmaf(xrow[384 + q * 4 + 2], w1.z, a1);
                a0 = fmaf(xrow[q * 4 + 3], w0.w, a0); a1 = fmaf(xrow[384 + q * 4 + 3], w1.w, a1);
            }
            cval[c] = __fadd_rn(__fadd_rn(__fadd_rn(a0, a1), a2),
                                b_enc[(size_t)g * SUB + sidx]);
        }
    }
    __syncthreads();

    // ---------------- Phase 3: per-group exact rank + scatter + decode ----------------
    for (int g = 0; g < NGROUPS; ++g) {
        const int gb = (g == 0) ? 0 : gend[g - 1];
        const int ge = gend[g];
        for (int t = gb + tid; t < ge; t += 256) {
            const unsigned mykey = fkey(cval[t]);
            const int mys = cidx[t] & 8191;
            int rank = 0;
            for (int e = gb; e < ge; ++e) {
                const unsigned ke = fkey(cval[e]);
                if (ke > mykey || (ke == mykey && (cidx[e] & 8191) < mys)) ++rank;
            }
            if (rank < TOPK) { sel_idx[rank] = mys; sel_val[rank] = fmaxf(cval[t], 0.f); }
        }
        __syncthreads();

        float* rowg = out_acts + b * NTOT + (size_t)g * SUB;
        if (tid < TOPK) rowg[sel_idx[tid]] = sel_val[tid];

        const float* Wg = W_dec + (size_t)g * SUB * D_MODEL + tid * 4;
#pragma unroll 8
        for (int j = 0; j < TOPK; ++j) {
            const float v = sel_val[j];
            const float4 wv = *(const float4*)(Wg + (size_t)sel_idx[j] * D_MODEL);
            r0 = fmaf(v, wv.x, r0); r1 = fmaf(v, wv.y, r1);
            r2 = fmaf(v, wv.z, r2); r3 = fmaf(v, wv.w, r3);
        }
        __syncthreads();
    }
    *(float4*)(out_recon + b * D_MODEL + tid * 4) = make_float4(r0, r1, r2, r3);
}

// ================= Fallback: R5 exact fp32 path (if ws too small) =================
#define PIDX(s) ((s) + ((s) >> 5))
#define BM 64
#define BN 128
#define BK 16
#define LDSA 68
#define LDSB 132

__global__ __launch_bounds__(256) void fb_encode_gemm(
    const float* __restrict__ x, const float* __restrict__ W_enc,
    const float* __restrict__ b_enc, float* __restrict__ out_acts)
{
    __shared__ float As[BK * LDSA];
    __shared__ float Bs[BK * LDSB];
    const int tid = threadIdx.x;
    const int nt = blockIdx.x, mt = blockIdx.y;
    const int g = nt >> 6, sbase = (nt & 63) * BN, mbase = mt * BM;
    const float* Bp = W_enc + ((size_t)g * D_MODEL) * SUB + sbase;
    const float* Ap = x + (size_t)mbase * D_MODEL;
    const int a_m = tid >> 2, a_c = (tid & 3) * 4;
    const int b_k = tid >> 5, b_c = (tid & 31) * 4;
    const int tr = tid >> 4, tc = tid & 15;
    float tot[4][8], cur[4][8];
#pragma unroll
    for (int i = 0; i < 4; ++i)
#pragma unroll
        for (int j = 0; j < 8; ++j) { tot[i][j] = 0.f; cur[i][j] = 0.f; }
#pragma unroll 1
    for (int it = 0; it < 64; ++it) {
        const int k0 = it * BK;
        const v4f va = *(const v4f*)(Ap + (size_t)a_m * D_MODEL + k0 + a_c);
        const v4f vb0 = *(const v4f*)(Bp + (size_t)(k0 + b_k) * SUB + b_c);
        const v4f vb1 = *(const v4f*)(Bp + (size_t)(k0 + b_k + 8) * SUB + b_c);
#pragma unroll
        for (int j = 0; j < 4; ++j) As[(a_c + j) * LDSA + a_m] = va[j];
        *(v4f*)&Bs[b_k * LDSB + b_c] = vb0;
        *(v4f*)&Bs[(b_k + 8) * LDSB + b_c] = vb1;
        __syncthreads();
        if (it == 24 || it == 48) {
#pragma unroll
            for (int i = 0; i < 4; ++i)
#pragma unroll
                for (int j = 0; j < 8; ++j) { tot[i][j] = __fadd_rn(tot[i][j], cur[i][j]); cur[i][j] = 0.f; }
        }
#pragma unroll
        for (int kk = 0; kk < BK; ++kk) {
            float a[4], bb[8];
            *(v4f*)&a[0] = *(const v4f*)&As[kk * LDSA + tr * 4];
            *(v4f*)&bb[0] = *(const v4f*)&Bs[kk * LDSB + tc * 4];
            *(v4f*)&bb[4] = *(const v4f*)&Bs[kk * LDSB + tc * 4 + 64];
#pragma unroll
            for (int i = 0; i < 4; ++i)
#pragma unroll
                for (int j = 0; j < 8; ++j) cur[i][j] = fmaf(a[i], bb[j], cur[i][j]);
        }
        __syncthreads();
    }
#pragma unroll
    for (int i = 0; i < 4; ++i)
#pragma unroll
        for (int j = 0; j < 8; ++j) tot[i][j] = __fadd_rn(tot[i][j], cur[i][j]);
    const float* bias = b_enc + (size_t)g * SUB + sbase;
    const float4 bb0 = *(const float4*)(bias + tc * 4);
    const float4 bb1 = *(const float4*)(bias + tc * 4 + 64);
    float* outp = out_acts + (size_t)g * SUB + sbase;
#pragma unroll
    for (int i = 0; i < 4; ++i) {
        const size_t row = (size_t)(mbase + tr * 4 + i);
        const float4 o0 = make_float4(__fadd_rn(tot[i][0], bb0.x), __fadd_rn(tot[i][1], bb0.y),
                                      __fadd_rn(tot[i][2], bb0.z), __fadd_rn(tot[i][3], bb0.w));
        const float4 o1 = make_float4(__fadd_rn(tot[i][4], bb1.x), __fadd_rn(tot[i][5], bb1.y),
                                      __fadd_rn(tot[i][6], bb1.z), __fadd_rn(tot[i][7], bb1.w));
        *(float4*)(outp + row * NTOT + tc * 4) = o0;
        *(float4*)(outp + row * NTOT + tc * 4 + 64) = o1;
    }
}

__global__ __launch_bounds__(256) void fb_topk_decode(
    const float* __restrict__ W_dec, float* __restrict__ out_recon,
    float* __restrict__ out_acts)
{
    __shared__ float row[SUB + (SUB >> 5)];
    __shared__ unsigned hist[256], sscan[256], wsum[4], wsum2[4];
    __shared__ unsigned sh_bin, sh_above;
    __shared__ int sel_idx[TOPK];
    __shared__ float sel_val[TOPK];
    const int tid = threadIdx.x, lane = tid & 63, w = tid >> 6;
    const size_t b = blockIdx.x;
    float r0 = 0.f, r1 = 0.f, r2 = 0.f, r3 = 0.f;
    for (int g = 0; g < NGROUPS; ++g) {
        float* rowg = out_acts + b * NTOT + (size_t)g * SUB;
#pragma unroll
        for (int t = 0; t < 8; ++t) {
            const int i4 = tid + t * 256;
            const float4 v = *(const float4*)(rowg + (size_t)i4 * 4);
            const int s0 = i4 * 4;
            row[PIDX(s0) + 0] = v.x; row[PIDX(s0) + 1] = v.y;
            row[PIDX(s0) + 2] = v.z; row[PIDX(s0) + 3] = v.w;
        }
        __syncthreads();
        unsigned prefix = 0, kwant = TOPK;
#pragma unroll
        for (int r = 0; r < 4; ++r) {
            const int shift = 24 - 8 * r;
            hist[tid] = 0;
            __syncthreads();
            for (int j = 0; j < 32; ++j) {
                const unsigned key = fkey(row[tid * 33 + j]);
                const unsigned hi = (unsigned)(((unsigned long long)key) >> (shift + 8));
                const unsigned pi = (unsigned)(((unsigned long long)prefix) >> (shift + 8));
                if (hi == pi) atomicAdd(&hist[(key >> shift) & 255u], 1u);
            }
            __syncthreads();
            unsigned s = hist[tid];
#pragma unroll
            for (int off = 1; off < 64; off <<= 1) {
                const unsigned o = __shfl_down(s, off, 64);
                if (lane + off < 64) s += o;
            }
            if (lane == 0) wsum[w] = s;
            __syncthreads();
            unsigned add = 0;
            for (int w2 = w + 1; w2 < 4; ++w2) add += wsum[w2];
            s += add;
            sscan[tid] = s;
            __syncthreads();
            const unsigned snext = (tid < 255) ? sscan[tid + 1] : 0u;
            if (s >= kwant && snext < kwant) { sh_bin = (unsigned)tid; sh_above = snext; }
            __syncthreads();
            prefix |= sh_bin << shift;
            kwant -= sh_above;
            __syncthreads();
        }
        const unsigned T = prefix, n_take = kwant, cnt_gt_total = TOPK - n_take;
        unsigned loc_gt = 0, loc_eq = 0;
        for (int j = 0; j < 32; ++j) {
            const unsigned key = fkey(row[tid * 33 + j]);
            loc_gt += (key > T); loc_eq += (key == T);
        }
        const unsigned pack = loc_gt | (loc_eq << 16);
        unsigned sI = pack;
#pragma unroll
        for (int off = 1; off < 64; off <<= 1) {
            const unsigned o = __shfl_up(sI, off, 64);
            if (lane >= off) sI += o;
        }
        if (lane == 63) wsum2[w] = sI;
        __syncthreads();
        unsigned woff = 0;
        for (int w2 = 0; w2 < w; ++w2) woff += wsum2[w2];
        const unsigned excl = sI - pack + woff;
        unsigned run_gt = excl & 0xFFFFu, run_eq = excl >> 16;
        for (int j = 0; j < 32; ++j) {
            const int sidx = tid * 32 + j;
            const float f = row[tid * 33 + j];
            const unsigned key = fkey(f);
            const float act = fmaxf(f, 0.f);
            if (key > T) { sel_idx[run_gt] = sidx; sel_val[run_gt] = act; ++run_gt; row[tid * 33 + j] = act; }
            else if (key == T) {
                if (run_eq < n_take) { sel_idx[cnt_gt_total + run_eq] = sidx; sel_val[cnt_gt_total + run_eq] = act; row[tid * 33 + j] = act; }
                else row[tid * 33 + j] = 0.f;
                ++run_eq;
            } else row[tid * 33 + j] = 0.f;
        }
        __syncthreads();
#pragma unroll
        for (int t = 0; t < 8; ++t) {
            const int i4 = tid + t * 256;
            const int s0 = i4 * 4;
            *(float4*)(rowg + (size_t)i4 * 4) =
                make_float4(row[PIDX(s0)], row[PIDX(s0) + 1], row[PIDX(s0) + 2], row[PIDX(s0) + 3]);
        }
        const float* Wg = W_dec + (size_t)g * SUB * D_MODEL + tid * 4;
#pragma unroll 8
        for (int j = 0; j < TOPK; ++j) {
            const float v = sel_val[j];
            const float4 wv = *(const float4*)(Wg + (size_t)sel_idx[j] * D_MODEL);
            r0 = fmaf(v, wv.x, r0); r1 = fmaf(v, wv.y, r1);
            r2 = fmaf(v, wv.z, r2); r3 = fmaf(v, wv.w, r3);
        }
        __syncthreads();
    }
    *(float4*)(out_recon + b * D_MODEL + tid * 4) = make_float4(r0, r1, r2, r3);
}

extern "C" void kernel_launch(void* const* d_in, const int* in_sizes, int n_in,
                              void* d_out, int out_size, void* d_ws, size_t ws_size,
                              hipStream_t stream) {
    const float* x     = (const float*)d_in[0];
    const float* W_enc = (const float*)d_in[1];
    const float* b_enc = (const float*)d_in[2];
    const float* W_dec = (const float*)d_in[3];

    float* out_recon = (float*)d_out;
    float* out_acts  = (float*)d_out + (size_t)BATCH * D_MODEL;

    const size_t WT_BYTES = (size_t)NGROUPS * SUB * D_MODEL * 4;   // 268 MB
    if (ws_size >= WT_BYTES) {
        float* WT = (float*)d_ws;
        transpose_wenc<<<dim3(SUB / 32, D_MODEL / 32, NGROUPS), 256, 0, stream>>>(W_enc, WT);
        mfma_scores<<<dim3(BATCH / 128, NTOT / 128), 256, 0, stream>>>(x, W_enc, b_enc, out_acts);
        select_decode<<<BATCH, 256, 0, stream>>>(x, WT, b_enc, W_dec, out_recon, out_acts);
    } else {
        fb_encode_gemm<<<dim3(NTOT / BN, BATCH / BM), 256, 0, stream>>>(x, W_enc, b_enc, out_acts);
        fb_topk_decode<<<BATCH, 256, 0, stream>>>(W_dec, out_recon, out_acts);
    }
}

// Round 13
// 1689.935 us; speedup vs baseline: 22.7139x; 1.0312x over previous
//
#include <hip/hip_runtime.h>

#define D_MODEL 1024
#define NGROUPS 8
#define SUB 8192
#define TOPK 32
#define BATCH 2048
#define NTOT (NGROUPS * SUB)   // 65536

typedef float v4f __attribute__((ext_vector_type(4)));
typedef _Float16 f16x8 __attribute__((ext_vector_type(8)));
typedef float f32x4 __attribute__((ext_vector_type(4)));

__device__ __forceinline__ unsigned fkey(float f) {
    unsigned u = __float_as_uint(f);
    return (u & 0x80000000u) ? ~u : (u | 0x80000000u);  // monotonic
}
__device__ __forceinline__ float inv_fkey(unsigned key) {
    unsigned u = (key & 0x80000000u) ? (key & 0x7FFFFFFFu) : ~key;
    return __uint_as_float(u);
}
__device__ __forceinline__ unsigned pack2h(float a, float b) {
    _Float16 ha = (_Float16)a, hb = (_Float16)b;
    return (unsigned)__builtin_bit_cast(unsigned short, ha)
         | ((unsigned)__builtin_bit_cast(unsigned short, hb) << 16);
}

// ===== k1 (tier1): W_enc [g][k][s] -> WT f32 [g][s][k] + WhT f16 [g][s][k] =====
__global__ __launch_bounds__(256) void transpose_wenc2(
    const float* __restrict__ W, float* __restrict__ WT, _Float16* __restrict__ WhT)
{
    __shared__ float t[32][33];
    const int g = blockIdx.z, kt = blockIdx.y, st = blockIdx.x;
    const int lx = threadIdx.x & 31, ly = threadIdx.x >> 5;
    const float* Wg = W + (size_t)g * D_MODEL * SUB;
    float* WTg = WT + (size_t)g * SUB * D_MODEL;
    _Float16* WhTg = WhT + (size_t)g * SUB * D_MODEL;
#pragma unroll
    for (int r = 0; r < 4; ++r)
        t[ly + 8 * r][lx] = Wg[(size_t)(kt * 32 + ly + 8 * r) * SUB + st * 32 + lx];
    __syncthreads();
#pragma unroll
    for (int r = 0; r < 4; ++r) {
        const float v = t[lx][ly + 8 * r];
        const size_t o = (size_t)(st * 32 + ly + 8 * r) * D_MODEL + kt * 32 + lx;
        WTg[o] = v;
        WhTg[o] = (_Float16)v;
    }
}

// ===== k2 (tier1): f16 MFMA scores from WhT; f16 scores into row's own out_acts slot =====
__global__ __launch_bounds__(256) void mfma_scores_h(
    const float* __restrict__ x, const _Float16* __restrict__ WhT,
    const float* __restrict__ b_enc, float* __restrict__ out_acts)
{
    __shared__ _Float16 Ah[128 * 40];
    __shared__ _Float16 Bh[128 * 40];

    const int tid = threadIdx.x;
    const int mt = blockIdx.x, nt = blockIdx.y;
    const int g = nt >> 6;
    const int sbase = (nt & 63) * 128;
    const int mbase = mt * 128;

    const int lane = tid & 63, w = tid >> 6;
    const int wm = w >> 1, wn = w & 1;
    const int l15 = lane & 15, grp = lane >> 4;

    const int am = tid >> 1, akh = (tid & 1) * 16;   // A staging
    const int bsr = tid >> 2, bk8 = (tid & 3) * 8;   // B staging (rows bsr, bsr+64)

    const _Float16* Bgp = WhT + ((size_t)g * SUB + sbase) * D_MODEL;

    f32x4 acc[4][4];
#pragma unroll
    for (int i = 0; i < 4; ++i)
#pragma unroll
        for (int j = 0; j < 4; ++j) acc[i][j] = (f32x4){0.f, 0.f, 0.f, 0.f};

#pragma unroll 1
    for (int it = 0; it < 32; ++it) {
        const int k0 = it * 32;
        const float* ap = x + (size_t)(mbase + am) * D_MODEL + k0 + akh;
        const v4f a0 = *(const v4f*)(ap);
        const v4f a1 = *(const v4f*)(ap + 4);
        const v4f a2 = *(const v4f*)(ap + 8);
        const v4f a3 = *(const v4f*)(ap + 12);
        const f16x8 b0 = *(const f16x8*)(Bgp + (size_t)bsr * D_MODEL + k0 + bk8);
        const f16x8 b1 = *(const f16x8*)(Bgp + (size_t)(bsr + 64) * D_MODEL + k0 + bk8);

        f16x8 v0, v1;
#pragma unroll
        for (int j = 0; j < 4; ++j) {
            v0[j] = (_Float16)a0[j]; v0[4 + j] = (_Float16)a1[j];
            v1[j] = (_Float16)a2[j]; v1[4 + j] = (_Float16)a3[j];
        }
        *(f16x8*)&Ah[am * 40 + akh]       = v0;
        *(f16x8*)&Ah[am * 40 + akh + 8]   = v1;
        *(f16x8*)&Bh[bsr * 40 + bk8]      = b0;
        *(f16x8*)&Bh[(bsr + 64) * 40 + bk8] = b1;
        __syncthreads();

        f16x8 af[4], bf[4];
#pragma unroll
        for (int i = 0; i < 4; ++i)
            af[i] = *(const f16x8*)&Ah[(wm * 64 + i * 16 + l15) * 40 + 8 * grp];
#pragma unroll
        for (int j = 0; j < 4; ++j)
            bf[j] = *(const f16x8*)&Bh[(wn * 64 + j * 16 + l15) * 40 + 8 * grp];
#pragma unroll
        for (int i = 0; i < 4; ++i)
#pragma unroll
            for (int j = 0; j < 4; ++j)
                acc[i][j] = __builtin_amdgcn_mfma_f32_16x16x32_f16(af[i], bf[j], acc[i][j], 0, 0, 0);
        __syncthreads();
    }

    float bb[4];
#pragma unroll
    for (int j = 0; j < 4; ++j)
        bb[j] = b_enc[(size_t)g * SUB + sbase + wn * 64 + j * 16 + l15];
#pragma unroll
    for (int i = 0; i < 4; ++i) {
        const int row = mbase + wm * 64 + i * 16 + grp * 4;
#pragma unroll
        for (int j = 0; j < 4; ++j) {
            const int colg = g * SUB + sbase + wn * 64 + j * 16 + l15;
#pragma unroll
            for (int r = 0; r < 4; ++r) {
                _Float16* hrow = (_Float16*)(out_acts + (size_t)(row + r) * NTOT);
                hrow[colg] = (_Float16)__fadd_rn(acc[i][j][r], bb[j]);
            }
        }
    }
}

// ===== k3 (tier1): f16-score select + parallel exact recompute + decode =====
#define CTOT 1024

__global__ __launch_bounds__(256) void select_decode_h(
    const float* __restrict__ x, const float* __restrict__ WT,
    const float* __restrict__ b_enc, const float* __restrict__ W_dec,
    float* __restrict__ out_recon, float* __restrict__ out_acts)
{
    __shared__ float xrow[1024];
    __shared__ unsigned hist[256], sscan[256], wsum[4];
    __shared__ unsigned sh_bin, sh_above, cand_cnt;
    __shared__ int   cidx[CTOT];      // (g<<13)|sidx
    __shared__ float cval[CTOT];
    __shared__ int   gend[NGROUPS];
    __shared__ int   sel_idx[TOPK];
    __shared__ float sel_val[TOPK];

    const int tid = threadIdx.x;
    const int lane = tid & 63;
    const int w = tid >> 6;
    const size_t b = blockIdx.x;

    *(float4*)&xrow[tid * 4] = *(const float4*)(x + b * D_MODEL + tid * 4);
    if (tid == 0) cand_cnt = 0;
    float r0 = 0.f, r1 = 0.f, r2 = 0.f, r3 = 0.f;

    const _Float16* hrow = (const _Float16*)(out_acts + b * NTOT);

    // ---- Phase 1a: per-group radix (2 rounds) + candidate append (NO zero yet) ----
    for (int g = 0; g < NGROUPS; ++g) {
        float sc[32];
#pragma unroll
        for (int t = 0; t < 4; ++t) {
            const f16x8 hv = *(const f16x8*)(hrow + (size_t)g * SUB + (size_t)(tid + t * 256) * 8);
#pragma unroll
            for (int e = 0; e < 8; ++e) sc[t * 8 + e] = (float)hv[e];
        }

        hist[tid] = 0;
        __syncthreads();
#pragma unroll
        for (int j = 0; j < 32; ++j)
            atomicAdd(&hist[fkey(sc[j]) >> 24], 1u);
        __syncthreads();

        unsigned prefix = 0, kwant = TOPK;
#pragma unroll
        for (int r = 0; r < 2; ++r) {
            unsigned s = hist[tid];
#pragma unroll
            for (int off = 1; off < 64; off <<= 1) {
                const unsigned o = __shfl_down(s, off, 64);
                if (lane + off < 64) s += o;
            }
            if (lane == 0) wsum[w] = s;
            __syncthreads();
            unsigned add = 0;
            for (int w2 = w + 1; w2 < 4; ++w2) add += wsum[w2];
            s += add;
            sscan[tid] = s;
            __syncthreads();
            const unsigned snext = (tid < 255) ? sscan[tid + 1] : 0u;
            if (s >= kwant && snext < kwant) { sh_bin = (unsigned)tid; sh_above = snext; }
            __syncthreads();
            const int shift = 24 - 8 * r;
            prefix |= sh_bin << shift;
            kwant -= sh_above;
            __syncthreads();
            if (r == 0) {
                hist[tid] = 0;
                __syncthreads();
#pragma unroll
                for (int j = 0; j < 32; ++j) {
                    const unsigned key = fkey(sc[j]);
                    if ((key >> 24) == (prefix >> 24))
                        atomicAdd(&hist[(key >> 16) & 255u], 1u);
                }
                __syncthreads();
            }
        }
        // floor(v32) - margin; margin 0.07 >= 2*(mfma 0.025 + f16-score 0.002) + slack
        const unsigned wkey = fkey(inv_fkey(prefix) - 0.07f);

#pragma unroll
        for (int j = 0; j < 32; ++j) {
            if (fkey(sc[j]) >= wkey) {
                const int sidx = (tid + (j >> 3) * 256) * 8 + (j & 7);
                const unsigned slot = atomicAdd(&cand_cnt, 1u);
                if (slot < CTOT) cidx[slot] = (g << 13) | sidx;
            }
        }
        __syncthreads();
        if (tid == 0) gend[g] = (int)min(cand_cnt, (unsigned)CTOT);
        __syncthreads();
    }

    // ---- Phase 1b: zero the full output row (scores consumed) ----
    float* rowb = out_acts + b * NTOT;
#pragma unroll 8
    for (int t = 0; t < 64; ++t)
        *(float4*)(rowb + (size_t)(tid + t * 256) * 4) = make_float4(0.f, 0.f, 0.f, 0.f);
    __syncthreads();

    // ---- Phase 2: one candidate per lane, BLAS-exact chains (3 interleaved) ----
    const int cnt = gend[NGROUPS - 1];
    for (int base = 0; base < cnt; base += 256) {
        const int c = base + tid;
        if (c < cnt) {
            const int id = cidx[c];
            const int g = id >> 13, sidx = id & 8191;
            const float* col = WT + ((size_t)g * SUB + sidx) * D_MODEL;
            float a0 = 0.f, a1 = 0.f, a2 = 0.f;
#pragma unroll 4
            for (int q = 0; q < 64; ++q) {
                const float4 w0 = *(const float4*)(col + q * 4);
                const float4 w1 = *(const float4*)(col + 384 + q * 4);
                const float4 w2 = *(const float4*)(col + 768 + q * 4);
                a0 = fmaf(xrow[q * 4 + 0], w0.x, a0); a1 = fmaf(xrow[384 + q * 4 + 0], w1.x, a1); a2 = fmaf(xrow[768 + q * 4 + 0], w2.x, a2);
                a0 = fmaf(xrow[q * 4 + 1], w0.y, a0); a1 = fmaf(xrow[384 + q * 4 + 1], w1.y, a1); a2 = fmaf(xrow[768 + q * 4 + 1], w2.y, a2);
                a0 = fmaf(xrow[q * 4 + 2], w0.z, a0); a1 = fmaf(xrow[384 + q * 4 + 2], w1.z, a1); a2 = fmaf(xrow[768 + q * 4 + 2], w2.z, a2);
                a0 = fmaf(xrow[q * 4 + 3], w0.w, a0); a1 = fmaf(xrow[384 + q * 4 + 3], w1.w, a1); a2 = fmaf(xrow[768 + q * 4 + 3], w2.w, a2);
            }
#pragma unroll 4
            for (int q = 64; q < 96; ++q) {
                const float4 w0 = *(const float4*)(col + q * 4);
                const float4 w1 = *(const float4*)(col + 384 + q * 4);
                a0 = fmaf(xrow[q * 4 + 0], w0.x, a0); a1 = fmaf(xrow[384 + q * 4 + 0], w1.x, a1);
                a0 = fmaf(xrow[q * 4 + 1], w0.y, a0); a1 = fmaf(xrow[384 + q * 4 + 1], w1.y, a1);
                a0 = fmaf(xrow[q * 4 + 2], w0.z, a0); a1 = fmaf(xrow[384 + q * 4 + 2], w1.z, a1);
                a0 = fmaf(xrow[q * 4 + 3], w0.w, a0); a1 = fmaf(xrow[384 + q * 4 + 3], w1.w, a1);
            }
            cval[c] = __fadd_rn(__fadd_rn(__fadd_rn(a0, a1), a2),
                                b_enc[(size_t)g * SUB + sidx]);
        }
    }
    __syncthreads();

    // ---- Phase 3: per-group exact rank + scatter + decode ----
    for (int g = 0; g < NGROUPS; ++g) {
        const int gb = (g == 0) ? 0 : gend[g - 1];
        const int ge = gend[g];
        for (int t = gb + tid; t < ge; t += 256) {
            const unsigned mykey = fkey(cval[t]);
            const int mys = cidx[t] & 8191;
            int rank = 0;
            for (int e = gb; e < ge; ++e) {
                const unsigned ke = fkey(cval[e]);
                if (ke > mykey || (ke == mykey && (cidx[e] & 8191) < mys)) ++rank;
            }
            if (rank < TOPK) { sel_idx[rank] = mys; sel_val[rank] = fmaxf(cval[t], 0.f); }
        }
        __syncthreads();

        float* rowg = out_acts + b * NTOT + (size_t)g * SUB;
        if (tid < TOPK) rowg[sel_idx[tid]] = sel_val[tid];

        const float* Wg = W_dec + (size_t)g * SUB * D_MODEL + tid * 4;
#pragma unroll 8
        for (int j = 0; j < TOPK; ++j) {
            const float v = sel_val[j];
            const float4 wv = *(const float4*)(Wg + (size_t)sel_idx[j] * D_MODEL);
            r0 = fmaf(v, wv.x, r0); r1 = fmaf(v, wv.y, r1);
            r2 = fmaf(v, wv.z, r2); r3 = fmaf(v, wv.w, r3);
        }
        __syncthreads();
    }
    *(float4*)(out_recon + b * D_MODEL + tid * 4) = make_float4(r0, r1, r2, r3);
}

// ===================== Tier 2 (R12 path): f32 scores =====================
__global__ __launch_bounds__(256) void transpose_wenc(
    const float* __restrict__ W, float* __restrict__ WT)
{
    __shared__ float t[32][33];
    const int g = blockIdx.z, kt = blockIdx.y, st = blockIdx.x;
    const int lx = threadIdx.x & 31, ly = threadIdx.x >> 5;
    const float* Wg = W + (size_t)g * D_MODEL * SUB;
    float* WTg = WT + (size_t)g * SUB * D_MODEL;
#pragma unroll
    for (int r = 0; r < 4; ++r)
        t[ly + 8 * r][lx] = Wg[(size_t)(kt * 32 + ly + 8 * r) * SUB + st * 32 + lx];
    __syncthreads();
#pragma unroll
    for (int r = 0; r < 4; ++r)
        WTg[(size_t)(st * 32 + ly + 8 * r) * D_MODEL + kt * 32 + lx] = t[lx][ly + 8 * r];
}

__global__ __launch_bounds__(256) void mfma_scores(
    const float* __restrict__ x, const float* __restrict__ W_enc,
    const float* __restrict__ b_enc, float* __restrict__ scores)
{
    __shared__ _Float16 Ah[128 * 40];
    __shared__ unsigned Bp[16 * 132];

    const int tid = threadIdx.x;
    const int mt = blockIdx.x, nt = blockIdx.y;
    const int g = nt >> 6;
    const int sbase = (nt & 63) * 128;
    const int mbase = mt * 128;

    const float* Bg = W_enc + (size_t)g * D_MODEL * SUB + sbase;
    const int lane = tid & 63, w = tid >> 6;
    const int wm = w >> 1, wn = w & 1;
    const int l15 = lane & 15, grp = lane >> 4;

    const int am = tid >> 1, akh = (tid & 1) * 16;
    const int bk4 = (tid >> 5) * 4, bs4 = (tid & 31) * 4;

    f32x4 acc[4][4];
#pragma unroll
    for (int i = 0; i < 4; ++i)
#pragma unroll
        for (int j = 0; j < 4; ++j) acc[i][j] = (f32x4){0.f, 0.f, 0.f, 0.f};

#pragma unroll 1
    for (int it = 0; it < 32; ++it) {
        const int k0 = it * 32;
        const float* ap = x + (size_t)(mbase + am) * D_MODEL + k0 + akh;
        const v4f a0 = *(const v4f*)(ap);
        const v4f a1 = *(const v4f*)(ap + 4);
        const v4f a2 = *(const v4f*)(ap + 8);
        const v4f a3 = *(const v4f*)(ap + 12);
        v4f br[4];
#pragma unroll
        for (int r = 0; r < 4; ++r)
            br[r] = *(const v4f*)(Bg + (size_t)(k0 + bk4 + r) * SUB + bs4);

        f16x8 v0, v1;
#pragma unroll
        for (int j = 0; j < 4; ++j) {
            v0[j] = (_Float16)a0[j]; v0[4 + j] = (_Float16)a1[j];
            v1[j] = (_Float16)a2[j]; v1[4 + j] = (_Float16)a3[j];
        }
        *(f16x8*)&Ah[am * 40 + akh]     = v0;
        *(f16x8*)&Ah[am * 40 + akh + 8] = v1;
        const int kp0 = bk4 >> 1;
        uint4 p0, p1;
        p0.x = pack2h(br[0][0], br[1][0]); p0.y = pack2h(br[0][1], br[1][1]);
        p0.z = pack2h(br[0][2], br[1][2]); p0.w = pack2h(br[0][3], br[1][3]);
        p1.x = pack2h(br[2][0], br[3][0]); p1.y = pack2h(br[2][1], br[3][1]);
        p1.z = pack2h(br[2][2], br[3][2]); p1.w = pack2h(br[2][3], br[3][3]);
        *(uint4*)&Bp[kp0 * 132 + bs4]       = p0;
        *(uint4*)&Bp[(kp0 + 1) * 132 + bs4] = p1;
        __syncthreads();

        f16x8 af[4], bf[4];
#pragma unroll
        for (int i = 0; i < 4; ++i)
            af[i] = *(const f16x8*)&Ah[(wm * 64 + i * 16 + l15) * 40 + 8 * grp];
#pragma unroll
        for (int j = 0; j < 4; ++j) {
            const int col = wn * 64 + j * 16 + l15;
            uint4 q;
            q.x = Bp[(4 * grp + 0) * 132 + col];
            q.y = Bp[(4 * grp + 1) * 132 + col];
            q.z = Bp[(4 * grp + 2) * 132 + col];
            q.w = Bp[(4 * grp + 3) * 132 + col];
            bf[j] = __builtin_bit_cast(f16x8, q);
        }
#pragma unroll
        for (int i = 0; i < 4; ++i)
#pragma unroll
            for (int j = 0; j < 4; ++j)
                acc[i][j] = __builtin_amdgcn_mfma_f32_16x16x32_f16(af[i], bf[j], acc[i][j], 0, 0, 0);
        __syncthreads();
    }

    float bb[4];
#pragma unroll
    for (int j = 0; j < 4; ++j)
        bb[j] = b_enc[(size_t)g * SUB + sbase + wn * 64 + j * 16 + l15];
#pragma unroll
    for (int i = 0; i < 4; ++i) {
        const int row = mbase + wm * 64 + i * 16 + grp * 4;
#pragma unroll
        for (int j = 0; j < 4; ++j) {
            const size_t col = (size_t)g * SUB + sbase + wn * 64 + j * 16 + l15;
#pragma unroll
            for (int r = 0; r < 4; ++r)
                scores[(size_t)(row + r) * NTOT + col] = __fadd_rn(acc[i][j][r], bb[j]);
        }
    }
}

__global__ __launch_bounds__(256) void select_decode(
    const float* __restrict__ x, const float* __restrict__ WT,
    const float* __restrict__ b_enc, const float* __restrict__ W_dec,
    float* __restrict__ out_recon, float* __restrict__ out_acts)
{
    __shared__ float xrow[1024];
    __shared__ unsigned hist[256], sscan[256], wsum[4];
    __shared__ unsigned sh_bin, sh_above, cand_cnt;
    __shared__ int   cidx[CTOT];
    __shared__ float cval[CTOT];
    __shared__ int   gend[NGROUPS];
    __shared__ int   sel_idx[TOPK];
    __shared__ float sel_val[TOPK];

    const int tid = threadIdx.x;
    const int lane = tid & 63;
    const int w = tid >> 6;
    const size_t b = blockIdx.x;

    *(float4*)&xrow[tid * 4] = *(const float4*)(x + b * D_MODEL + tid * 4);
    if (tid == 0) cand_cnt = 0;
    float r0 = 0.f, r1 = 0.f, r2 = 0.f, r3 = 0.f;

    for (int g = 0; g < NGROUPS; ++g) {
        float* rowg = out_acts + b * NTOT + (size_t)g * SUB;
        float sc[32];
#pragma unroll
        for (int t = 0; t < 8; ++t)
            *(v4f*)&sc[t * 4] = *(const v4f*)(rowg + (size_t)(tid + t * 256) * 4);

        hist[tid] = 0;
        __syncthreads();
#pragma unroll
        for (int j = 0; j < 32; ++j)
            atomicAdd(&hist[fkey(sc[j]) >> 24], 1u);
        __syncthreads();

        unsigned prefix = 0, kwant = TOPK;
#pragma unroll
        for (int r = 0; r < 2; ++r) {
            unsigned s = hist[tid];
#pragma unroll
            for (int off = 1; off < 64; off <<= 1) {
                const unsigned o = __shfl_down(s, off, 64);
                if (lane + off < 64) s += o;
            }
            if (lane == 0) wsum[w] = s;
            __syncthreads();
            unsigned add = 0;
            for (int w2 = w + 1; w2 < 4; ++w2) add += wsum[w2];
            s += add;
            sscan[tid] = s;
            __syncthreads();
            const unsigned snext = (tid < 255) ? sscan[tid + 1] : 0u;
            if (s >= kwant && snext < kwant) { sh_bin = (unsigned)tid; sh_above = snext; }
            __syncthreads();
            const int shift = 24 - 8 * r;
            prefix |= sh_bin << shift;
            kwant -= sh_above;
            __syncthreads();
            if (r == 0) {
                hist[tid] = 0;
                __syncthreads();
#pragma unroll
                for (int j = 0; j < 32; ++j) {
                    const unsigned key = fkey(sc[j]);
                    if ((key >> 24) == (prefix >> 24))
                        atomicAdd(&hist[(key >> 16) & 255u], 1u);
                }
                __syncthreads();
            }
        }
        const unsigned wkey = fkey(inv_fkey(prefix) - 0.06f);

#pragma unroll
        for (int j = 0; j < 32; ++j) {
            if (fkey(sc[j]) >= wkey) {
                const int sidx = (tid + (j >> 2) * 256) * 4 + (j & 3);
                const unsigned slot = atomicAdd(&cand_cnt, 1u);
                if (slot < CTOT) cidx[slot] = (g << 13) | sidx;
            }
        }
#pragma unroll
        for (int t = 0; t < 8; ++t)
            *(float4*)(rowg + (size_t)(tid + t * 256) * 4) = make_float4(0.f, 0.f, 0.f, 0.f);
        __syncthreads();
        if (tid == 0) gend[g] = (int)min(cand_cnt, (unsigned)CTOT);
        __syncthreads();
    }

    const int cnt = gend[NGROUPS - 1];
    for (int base = 0; base < cnt; base += 256) {
        const int c = base + tid;
        if (c < cnt) {
            const int id = cidx[c];
            const int g = id >> 13, sidx = id & 8191;
            const float* col = WT + ((size_t)g * SUB + sidx) * D_MODEL;
            float a0 = 0.f, a1 = 0.f, a2 = 0.f;
#pragma unroll 4
            for (int q = 0; q < 64; ++q) {
                const float4 w0 = *(const float4*)(col + q * 4);
                const float4 w1 = *(const float4*)(col + 384 + q * 4);
                const float4 w2 = *(const float4*)(col + 768 + q * 4);
                a0 = fmaf(xrow[q * 4 + 0], w0.x, a0); a1 = fmaf(xrow[384 + q * 4 + 0], w1.x, a1); a2 = fmaf(xrow[768 + q * 4 + 0], w2.x, a2);
                a0 = fmaf(xrow[q * 4 + 1], w0.y, a0); a1 = fmaf(xrow[384 + q * 4 + 1], w1.y, a1); a2 = fmaf(xrow[768 + q * 4 + 1], w2.y, a2);
                a0 = fmaf(xrow[q * 4 + 2], w0.z, a0); a1 = fmaf(xrow[384 + q * 4 + 2], w1.z, a1); a2 = fmaf(xrow[768 + q * 4 + 2], w2.z, a2);
                a0 = fmaf(xrow[q * 4 + 3], w0.w, a0); a1 = fmaf(xrow[384 + q * 4 + 3], w1.w, a1); a2 = fmaf(xrow[768 + q * 4 + 3], w2.w, a2);
            }
#pragma unroll 4
            for (int q = 64; q < 96; ++q) {
                const float4 w0 = *(const float4*)(col + q * 4);
                const float4 w1 = *(const float4*)(col + 384 + q * 4);
                a0 = fmaf(xrow[q * 4 + 0], w0.x, a0); a1 = fmaf(xrow[384 + q * 4 + 0], w1.x, a1);
                a0 = fmaf(xrow[q * 4 + 1], w0.y, a0); a1 = fmaf(xrow[384 + q * 4 + 1], w1.y, a1);
                a0 = fmaf(xrow[q * 4 + 2], w0.z, a0); a1 = fmaf(xrow[384 + q * 4 + 2], w1.z, a1);
                a0 = fmaf(xrow[q * 4 + 3], w0.w, a0); a1 = fmaf(xrow[384 + q * 4 + 3], w1.w, a1);
            }
            cval[c] = __fadd_rn(__fadd_rn(__fadd_rn(a0, a1), a2),
                                b_enc[(size_t)g * SUB + sidx]);
        }
    }
    __syncthreads();

    for (int g = 0; g < NGROUPS; ++g) {
        const int gb = (g == 0) ? 0 : gend[g - 1];
        const int ge = gend[g];
        for (int t = gb + tid; t < ge; t += 256) {
            const unsigned mykey = fkey(cval[t]);
            const int mys = cidx[t] & 8191;
            int rank = 0;
            for (int e = gb; e < ge; ++e) {
                const unsigned ke = fkey(cval[e]);
                if (ke > mykey || (ke == mykey && (cidx[e] & 8191) < mys)) ++rank;
            }
            if (rank < TOPK) { sel_idx[rank] = mys; sel_val[rank] = fmaxf(cval[t], 0.f); }
        }
        __syncthreads();

        float* rowg = out_acts + b * NTOT + (size_t)g * SUB;
        if (tid < TOPK) rowg[sel_idx[tid]] = sel_val[tid];

        const float* Wg = W_dec + (size_t)g * SUB * D_MODEL + tid * 4;
#pragma unroll 8
        for (int j = 0; j < TOPK; ++j) {
            const float v = sel_val[j];
            const float4 wv = *(const float4*)(Wg + (size_t)sel_idx[j] * D_MODEL);
            r0 = fmaf(v, wv.x, r0); r1 = fmaf(v, wv.y, r1);
            r2 = fmaf(v, wv.z, r2); r3 = fmaf(v, wv.w, r3);
        }
        __syncthreads();
    }
    *(float4*)(out_recon + b * D_MODEL + tid * 4) = make_float4(r0, r1, r2, r3);
}

// ===================== Tier 3: R5 exact fp32 fallback =====================
#define PIDX(s) ((s) + ((s) >> 5))
#define BM 64
#define BN 128
#define BK 16
#define LDSA 68
#define LDSB 132

__global__ __launch_bounds__(256) void fb_encode_gemm(
    const float* __restrict__ x, const float* __restrict__ W_enc,
    const float* __restrict__ b_enc, float* __restrict__ out_acts)
{
    __shared__ float As[BK * LDSA];
    __shared__ float Bs[BK * LDSB];
    const int tid = threadIdx.x;
    const int nt = blockIdx.x, mt = blockIdx.y;
    const int g = nt >> 6, sbase = (nt & 63) * BN, mbase = mt * BM;
    const float* Bp = W_enc + ((size_t)g * D_MODEL) * SUB + sbase;
    const float* Ap = x + (size_t)mbase * D_MODEL;
    const int a_m = tid >> 2, a_c = (tid & 3) * 4;
    const int b_k = tid >> 5, b_c = (tid & 31) * 4;
    const int tr = tid >> 4, tc = tid & 15;
    float tot[4][8], cur[4][8];
#pragma unroll
    for (int i = 0; i < 4; ++i)
#pragma unroll
        for (int j = 0; j < 8; ++j) { tot[i][j] = 0.f; cur[i][j] = 0.f; }
#pragma unroll 1
    for (int it = 0; it < 64; ++it) {
        const int k0 = it * BK;
        const v4f va = *(const v4f*)(Ap + (size_t)a_m * D_MODEL + k0 + a_c);
        const v4f vb0 = *(const v4f*)(Bp + (size_t)(k0 + b_k) * SUB + b_c);
        const v4f vb1 = *(const v4f*)(Bp + (size_t)(k0 + b_k + 8) * SUB + b_c);
#pragma unroll
        for (int j = 0; j < 4; ++j) As[(a_c + j) * LDSA + a_m] = va[j];
        *(v4f*)&Bs[b_k * LDSB + b_c] = vb0;
        *(v4f*)&Bs[(b_k + 8) * LDSB + b_c] = vb1;
        __syncthreads();
        if (it == 24 || it == 48) {
#pragma unroll
            for (int i = 0; i < 4; ++i)
#pragma unroll
                for (int j = 0; j < 8; ++j) { tot[i][j] = __fadd_rn(tot[i][j], cur[i][j]); cur[i][j] = 0.f; }
        }
#pragma unroll
        for (int kk = 0; kk < BK; ++kk) {
            float a[4], bb[8];
            *(v4f*)&a[0] = *(const v4f*)&As[kk * LDSA + tr * 4];
            *(v4f*)&bb[0] = *(const v4f*)&Bs[kk * LDSB + tc * 4];
            *(v4f*)&bb[4] = *(const v4f*)&Bs[kk * LDSB + tc * 4 + 64];
#pragma unroll
            for (int i = 0; i < 4; ++i)
#pragma unroll
                for (int j = 0; j < 8; ++j) cur[i][j] = fmaf(a[i], bb[j], cur[i][j]);
        }
        __syncthreads();
    }
#pragma unroll
    for (int i = 0; i < 4; ++i)
#pragma unroll
        for (int j = 0; j < 8; ++j) tot[i][j] = __fadd_rn(tot[i][j], cur[i][j]);
    const float* bias = b_enc + (size_t)g * SUB + sbase;
    const float4 bb0 = *(const float4*)(bias + tc * 4);
    const float4 bb1 = *(const float4*)(bias + tc * 4 + 64);
    float* outp = out_acts + (size_t)g * SUB + sbase;
#pragma unroll
    for (int i = 0; i < 4; ++i) {
        const size_t row = (size_t)(mbase + tr * 4 + i);
        const float4 o0 = make_float4(__fadd_rn(tot[i][0], bb0.x), __fadd_rn(tot[i][1], bb0.y),
                                      __fadd_rn(tot[i][2], bb0.z), __fadd_rn(tot[i][3], bb0.w));
        const float4 o1 = make_float4(__fadd_rn(tot[i][4], bb1.x), __fadd_rn(tot[i][5], bb1.y),
                                      __fadd_rn(tot[i][6], bb1.z), __fadd_rn(tot[i][7], bb1.w));
        *(float4*)(outp + row * NTOT + tc * 4) = o0;
        *(float4*)(outp + row * NTOT + tc * 4 + 64) = o1;
    }
}

__global__ __launch_bounds__(256) void fb_topk_decode(
    const float* __restrict__ W_dec, float* __restrict__ out_recon,
    float* __restrict__ out_acts)
{
    __shared__ float row[SUB + (SUB >> 5)];
    __shared__ unsigned hist[256], sscan[256], wsum[4], wsum2[4];
    __shared__ unsigned sh_bin, sh_above;
    __shared__ int sel_idx[TOPK];
    __shared__ float sel_val[TOPK];
    const int tid = threadIdx.x, lane = tid & 63, w = tid >> 6;
    const size_t b = blockIdx.x;
    float r0 = 0.f, r1 = 0.f, r2 = 0.f, r3 = 0.f;
    for (int g = 0; g < NGROUPS; ++g) {
        float* rowg = out_acts + b * NTOT + (size_t)g * SUB;
#pragma unroll
        for (int t = 0; t < 8; ++t) {
            const int i4 = tid + t * 256;
            const float4 v = *(const float4*)(rowg + (size_t)i4 * 4);
            const int s0 = i4 * 4;
            row[PIDX(s0) + 0] = v.x; row[PIDX(s0) + 1] = v.y;
            row[PIDX(s0) + 2] = v.z; row[PIDX(s0) + 3] = v.w;
        }
        __syncthreads();
        unsigned prefix = 0, kwant = TOPK;
#pragma unroll
        for (int r = 0; r < 4; ++r) {
            const int shift = 24 - 8 * r;
            hist[tid] = 0;
            __syncthreads();
            for (int j = 0; j < 32; ++j) {
                const unsigned key = fkey(row[tid * 33 + j]);
                const unsigned hi = (unsigned)(((unsigned long long)key) >> (shift + 8));
                const unsigned pi = (unsigned)(((unsigned long long)prefix) >> (shift + 8));
                if (hi == pi) atomicAdd(&hist[(key >> shift) & 255u], 1u);
            }
            __syncthreads();
            unsigned s = hist[tid];
#pragma unroll
            for (int off = 1; off < 64; off <<= 1) {
                const unsigned o = __shfl_down(s, off, 64);
                if (lane + off < 64) s += o;
            }
            if (lane == 0) wsum[w] = s;
            __syncthreads();
            unsigned add = 0;
            for (int w2 = w + 1; w2 < 4; ++w2) add += wsum[w2];
            s += add;
            sscan[tid] = s;
            __syncthreads();
            const unsigned snext = (tid < 255) ? sscan[tid + 1] : 0u;
            if (s >= kwant && snext < kwant) { sh_bin = (unsigned)tid; sh_above = snext; }
            __syncthreads();
            prefix |= sh_bin << shift;
            kwant -= sh_above;
            __syncthreads();
        }
        const unsigned T = prefix, n_take = kwant, cnt_gt_total = TOPK - n_take;
        unsigned loc_gt = 0, loc_eq = 0;
        for (int j = 0; j < 32; ++j) {
            const unsigned key = fkey(row[tid * 33 + j]);
            loc_gt += (key > T); loc_eq += (key == T);
        }
        const unsigned pack = loc_gt | (loc_eq << 16);
        unsigned sI = pack;
#pragma unroll
        for (int off = 1; off < 64; off <<= 1) {
            const unsigned o = __shfl_up(sI, off, 64);
            if (lane >= off) sI += o;
        }
        if (lane == 63) wsum2[w] = sI;
        __syncthreads();
        unsigned woff = 0;
        for (int w2 = 0; w2 < w; ++w2) woff += wsum2[w2];
        const unsigned excl = sI - pack + woff;
        unsigned run_gt = excl & 0xFFFFu, run_eq = excl >> 16;
        for (int j = 0; j < 32; ++j) {
            const int sidx = tid * 32 + j;
            const float f = row[tid * 33 + j];
            const unsigned key = fkey(f);
            const float act = fmaxf(f, 0.f);
            if (key > T) { sel_idx[run_gt] = sidx; sel_val[run_gt] = act; ++run_gt; row[tid * 33 + j] = act; }
            else if (key == T) {
                if (run_eq < n_take) { sel_idx[cnt_gt_total + run_eq] = sidx; sel_val[cnt_gt_total + run_eq] = act; row[tid * 33 + j] = act; }
                else row[tid * 33 + j] = 0.f;
                ++run_eq;
            } else row[tid * 33 + j] = 0.f;
        }
        __syncthreads();
#pragma unroll
        for (int t = 0; t < 8; ++t) {
            const int i4 = tid + t * 256;
            const int s0 = i4 * 4;
            *(float4*)(rowg + (size_t)i4 * 4) =
                make_float4(row[PIDX(s0)], row[PIDX(s0) + 1], row[PIDX(s0) + 2], row[PIDX(s0) + 3]);
        }
        const float* Wg = W_dec + (size_t)g * SUB * D_MODEL + tid * 4;
#pragma unroll 8
        for (int j = 0; j < TOPK; ++j) {
            const float v = sel_val[j];
            const float4 wv = *(const float4*)(Wg + (size_t)sel_idx[j] * D_MODEL);
            r0 = fmaf(v, wv.x, r0); r1 = fmaf(v, wv.y, r1);
            r2 = fmaf(v, wv.z, r2); r3 = fmaf(v, wv.w, r3);
        }
        __syncthreads();
    }
    *(float4*)(out_recon + b * D_MODEL + tid * 4) = make_float4(r0, r1, r2, r3);
}

extern "C" void kernel_launch(void* const* d_in, const int* in_sizes, int n_in,
                              void* d_out, int out_size, void* d_ws, size_t ws_size,
                              hipStream_t stream) {
    const float* x     = (const float*)d_in[0];
    const float* W_enc = (const float*)d_in[1];
    const float* b_enc = (const float*)d_in[2];
    const float* W_dec = (const float*)d_in[3];

    float* out_recon = (float*)d_out;
    float* out_acts  = (float*)d_out + (size_t)BATCH * D_MODEL;

    const size_t WT_BYTES = (size_t)NGROUPS * SUB * D_MODEL * 4;   // 268 MB
    const size_t WH_BYTES = (size_t)NGROUPS * SUB * D_MODEL * 2;   // 134 MB

    if (ws_size >= WT_BYTES + WH_BYTES) {
        float* WT = (float*)d_ws;
        _Float16* WhT = (_Float16*)((char*)d_ws + WT_BYTES);
        transpose_wenc2<<<dim3(SUB / 32, D_MODEL / 32, NGROUPS), 256, 0, stream>>>(W_enc, WT, WhT);
        mfma_scores_h<<<dim3(BATCH / 128, NTOT / 128), 256, 0, stream>>>(x, WhT, b_enc, out_acts);
        select_decode_h<<<BATCH, 256, 0, stream>>>(x, WT, b_enc, W_dec, out_recon, out_acts);
    } else if (ws_size >= WT_BYTES) {
        float* WT = (float*)d_ws;
        transpose_wenc<<<dim3(SUB / 32, D_MODEL / 32, NGROUPS), 256, 0, stream>>>(W_enc, WT);
        mfma_scores<<<dim3(BATCH / 128, NTOT / 128), 256, 0, stream>>>(x, W_enc, b_enc, out_acts);
        select_decode<<<BATCH, 256, 0, stream>>>(x, WT, b_enc, W_dec, out_recon, out_acts);
    } else {
        fb_encode_gemm<<<dim3(NTOT / BN, BATCH / BM), 256, 0, stream>>>(x, W_enc, b_enc, out_acts);
        fb_topk_decode<<<BATCH, 256, 0, stream>>>(W_dec, out_recon, out_acts);
    }
}